// Round 2
// baseline (462.371 us; speedup 1.0000x reference)
//
#include <hip/hip_runtime.h>
#include <hip/hip_bf16.h>

#define HW 9216      // 96*96

typedef unsigned short ushort;
typedef unsigned int   uint;
typedef __attribute__((ext_vector_type(4))) float f32x4;
typedef __attribute__((ext_vector_type(2))) uint  u32x2;
typedef __attribute__((ext_vector_type(8))) short s16x8;

// ---------------- module-global intermediates (BSS) ----------------
__device__ float  g_o1[4*32*HW];                 // conv1 out (bias+relu) fp32
__device__ float  g_q [2*4*26*HW];               // conv2 split-K partials (bias in kg0)
__device__ __align__(16) float g_ht[4*HW*96];    // hp transposed: [b][spatial][c] fp32
__device__ __align__(16) ushort g_chi[4*(size_t)HW*128]; // concat [x;hp] transposed, bf16 HI, ch-pad to 128
__device__ __align__(16) ushort g_clo[4*(size_t)HW*128]; // bf16 LO residual
__device__ __align__(16) ushort g_w1b[25*4*2048];        // conv1 W: [(tap*4+cb)][hl][nt][16oc][32k] bf16
__device__ __align__(16) ushort g_a[36864*1248]; // M-matrix, bf16, MFMA A-frag swizzle
__device__ __align__(16) ushort g_b[18*39*512];  // weights,  bf16, MFMA B-frag swizzle
__device__ __align__(16) float  g_urv[2304*288*16]; // GEMM out, tile-major [pt][n][16px]

__device__ __forceinline__ ushort f2b(float f){  // fp32 -> bf16 bits, RNE
  uint x = __float_as_uint(f);
  return (ushort)((x + 0x7FFFu + ((x >> 16) & 1u)) >> 16);
}
__device__ __forceinline__ float b2f(ushort h){
  return __uint_as_float(((uint)h) << 16);
}

// ---------------- K0: pack 1x1 weights into B-fragment swizzle
// K-ordering PERMUTED: k' = l*96 + c  (weight flat index = c*13 + l)
__global__ void pack_b_k(const float* __restrict__ uww, const float* __restrict__ rww,
                         const float* __restrict__ vww){
  int i = blockIdx.x*256 + threadIdx.x;
  if (i >= 3*96*1248) return;
  int gate = i / (96*1248); int rem = i % (96*1248);
  int oc = rem / 1248;      int kp = rem % 1248;   // k' position
  int l = kp / 96, c = kp % 96;
  const float* src = (gate == 0) ? uww : ((gate == 1) ? rww : vww);
  float v = src[oc*1248 + c*13 + l];
  int n  = gate*96 + oc;
  int nt = n >> 4, nl = n & 15;
  int kb = kp >> 5, kk = kp & 31;
  g_b[(nt*39 + kb)*512 + nl*32 + kk] = f2b(v);
}

// ---------------- K0a: pack conv1 weights -> bf16 hi/lo MFMA B-fragments
// sw1 layout: (32 oc, 104 ci, 5, 5). Pad ci to 128 with zeros (makes g_c* pad inert).
__global__ void pack_w1b_k(const float* __restrict__ w1){
  int i = blockIdx.x*256 + threadIdx.x;
  if (i >= 25*4*1024) return;
  int tap = i >> 12;
  int cb  = (i >> 10) & 3;
  int oc  = (i >> 5) & 31;
  int kk  = i & 31;
  int ci  = cb*32 + kk;
  float w = (ci < 104) ? w1[oc*2600 + ci*25 + tap] : 0.f;
  ushort h = f2b(w);
  float rem = w - b2f(h);
  int base = ((tap*4 + cb) << 11) + (oc >> 4)*512 + (oc & 15)*32 + kk;
  g_w1b[base]        = h;         // hi
  g_w1b[base + 1024] = f2b(rem);  // lo
}

// ---------------- K0b: transpose hp (B,C,HW) -> g_ht (fp32) + g_chi/g_clo (bf16, ch 8..103)
//                 blockIdx.y==3 handles x -> g_chi/g_clo ch 0..7
__global__ __launch_bounds__(256) void transpose_k(const float* __restrict__ hp,
                                                   const float* __restrict__ x){
  __shared__ float tile[32][33];
  int s0 = blockIdx.x*32;          // spatial tile
  int b  = blockIdx.z;
  int t  = threadIdx.x;
  if (blockIdx.y < 3){
    int c0 = blockIdx.y*32;        // channel tile (96 = 3*32)
    for (int i = t; i < 32*32; i += 256){
      int c = i >> 5, s = i & 31;
      tile[c][s] = hp[((size_t)(b*96 + c0 + c))*HW + s0 + s];
    }
    __syncthreads();
    for (int i = t; i < 32*32; i += 256){
      int s = i >> 5, c = i & 31;
      float v = tile[c][s];
      size_t px = (size_t)b*HW + s0 + s;
      g_ht[px*96 + c0 + c] = v;
      ushort h = f2b(v);
      g_chi[px*128 + 8 + c0 + c] = h;
      g_clo[px*128 + 8 + c0 + c] = f2b(v - b2f(h));
    }
  } else {
    for (int i = t; i < 8*32; i += 256){
      int c = i >> 5, s = i & 31;
      tile[c][s] = x[((size_t)(b*8 + c))*HW + s0 + s];
    }
    __syncthreads();
    for (int i = t; i < 32*8; i += 256){
      int s = i >> 3, c = i & 7;
      float v = tile[c][s];
      size_t px = (size_t)b*HW + s0 + s;
      ushort h = f2b(v);
      g_chi[px*128 + c] = h;
      g_clo[px*128 + c] = f2b(v - b2f(h));
    }
  }
}

// ---------------- K1: conv1 5x5 pad2 (104ch->32ch) via MFMA, 3-term bf16 split
// (fp32-faithful: out += ahi*bhi + alo*bhi + ahi*blo). One wave per block,
// NO barriers (single-wave LDS ordering via compiler waitcnt).
// Tile: 4 rows x 16 cols of pixels. All 4 channel-blocks staged up front
// (one latency exposure); B-fragments software-pipelined at distance 2.
// LDS swizzle: chunk c stored at source-chunk (c^px)&3; since px == kx+nl (mod 4),
// the read swizzle is mr-independent -> ds offsets fold into immediates.
__device__ __forceinline__ void stage_all(ushort* shh, ushort* shl, int j,
                                          int r0, int c0, size_t pbase){
  int px = j >> 2, c = j & 3;            // px 0..159 (8x20 halo), chunk 0..3
  int r = px / 20, cc = px - r*20;
  int gr = r0 + r - 2, gc = c0 + cc - 2;
  bool ok = ((unsigned)gr < 96u) && ((unsigned)gc < 96u);
  int go  = ok ? (gr*96 + gc) : 0;
  int sw  = ((c ^ px) & 3) << 4;         // source-side swizzle (bytes)
  size_t goff = ((pbase + (size_t)go) << 8) + (size_t)sw;   // px*128ch*2B
  const char* sh8 = (const char*)g_chi + goff;
  const char* sl8 = (const char*)g_clo + goff;
  int lo = px*64 + c*16;                 // linear LDS offset (bytes)
  #pragma unroll
  for (int cb = 0; cb < 4; cb++){
    f32x4 vh = (f32x4){0.f,0.f,0.f,0.f}, vl = (f32x4){0.f,0.f,0.f,0.f};
    if (ok){
      vh = *(const f32x4*)(sh8 + cb*64);
      vl = *(const f32x4*)(sl8 + cb*64);
    }
    *(f32x4*)((char*)shh + cb*10240 + lo) = vh;
    *(f32x4*)((char*)shl + cb*10240 + lo) = vl;
  }
}

__global__ __launch_bounds__(64) void conv1_mfma_k(const float* __restrict__ b1){
  __shared__ __align__(16) ushort sh_hi[4*160*32];   // 40 KB
  __shared__ __align__(16) ushort sh_lo[4*160*32];   // 40 KB
  int rt = blockIdx.x / 6, ct = blockIdx.x % 6;      // 24 row-tiles x 6 col-tiles
  int b  = blockIdx.z;
  int t  = threadIdx.x;                              // single wave: t == lane
  int nl = t & 15, q = t >> 4;
  int foff = nl*32 + q*8;                            // B-frag lane offset (shorts)
  int r0 = rt*4, c0 = ct*16;
  const size_t pbase = (size_t)b*HW;

  // ---- stage entire 8x20 halo, all 4 channel-blocks, hi+lo: one exposure
  #pragma unroll
  for (int it = 0; it < 10; it++) stage_all(sh_hi, sh_lo, it*64 + t, r0, c0, pbase);

  f32x4 acc[4][2];
  #pragma unroll
  for (int mr = 0; mr < 4; mr++){
    acc[mr][0] = (f32x4){0.f,0.f,0.f,0.f};
    acc[mr][1] = (f32x4){0.f,0.f,0.f,0.f};
  }

  for (int cb = 0; cb < 4; cb++){
    const char* shh = (const char*)sh_hi + cb*10240;
    const char* shl = (const char*)sh_lo + cb*10240;
    const ushort* bpc = g_w1b + ((size_t)cb << 11);

    // B-fragment pipeline, distance 2 (3-slot rotation, statically unrolled)
    s16x8 bq[3][4];
#define LOADB(slot, tap) { const ushort* bp = bpc + ((size_t)(tap) << 13); \
    bq[slot][0] = *(const s16x8*)(bp + foff); \
    bq[slot][1] = *(const s16x8*)(bp + 512 + foff); \
    bq[slot][2] = *(const s16x8*)(bp + 1024 + foff); \
    bq[slot][3] = *(const s16x8*)(bp + 1536 + foff); }
    LOADB(0, 0); LOADB(1, 1);

    #pragma unroll
    for (int tp = 0; tp < 25; tp++){
      int cur = tp % 3, nxt = (tp + 2) % 3;
      if (tp < 23) LOADB(nxt, tp + 2);
      int ky = tp / 5, kx = tp % 5;

      int u  = kx + nl;
      int lb = (u << 6) + (((q ^ u) & 3) << 4);   // read-side swizzle (mr-indep)
      const char* ph = shh + lb;
      const char* pl = shl + lb;
      s16x8 ah[4], al[4];
      #pragma unroll
      for (int mr = 0; mr < 4; mr++){
        ah[mr] = *(const s16x8*)(ph + (mr + ky)*1280);
        al[mr] = *(const s16x8*)(pl + (mr + ky)*1280);
      }
      #pragma unroll
      for (int mr = 0; mr < 4; mr++){
        acc[mr][0] = __builtin_amdgcn_mfma_f32_16x16x32_bf16(ah[mr], bq[cur][0], acc[mr][0], 0,0,0);
        acc[mr][1] = __builtin_amdgcn_mfma_f32_16x16x32_bf16(ah[mr], bq[cur][1], acc[mr][1], 0,0,0);
      }
      #pragma unroll
      for (int mr = 0; mr < 4; mr++){
        acc[mr][0] = __builtin_amdgcn_mfma_f32_16x16x32_bf16(al[mr], bq[cur][0], acc[mr][0], 0,0,0);
        acc[mr][1] = __builtin_amdgcn_mfma_f32_16x16x32_bf16(al[mr], bq[cur][1], acc[mr][1], 0,0,0);
      }
      #pragma unroll
      for (int mr = 0; mr < 4; mr++){
        acc[mr][0] = __builtin_amdgcn_mfma_f32_16x16x32_bf16(ah[mr], bq[cur][2], acc[mr][0], 0,0,0);
        acc[mr][1] = __builtin_amdgcn_mfma_f32_16x16x32_bf16(ah[mr], bq[cur][3], acc[mr][1], 0,0,0);
      }
    }
#undef LOADB
  }

  // epilogue: bias + relu, direct to g_o1
  #pragma unroll
  for (int nt = 0; nt < 2; nt++){
    int oc = nt*16 + nl;
    float bias = b1[oc];
    float* dst = g_o1 + ((size_t)(b*32 + oc))*HW + (size_t)r0*96 + c0 + q*4;
    #pragma unroll
    for (int mr = 0; mr < 4; mr++){
      f32x4 v = acc[mr][nt];
      v.x = fmaxf(v.x + bias, 0.f); v.y = fmaxf(v.y + bias, 0.f);
      v.z = fmaxf(v.z + bias, 0.f); v.w = fmaxf(v.w + bias, 0.f);
      *(f32x4*)(dst + mr*96) = v;
    }
  }
}

// ---------------- K3: conv2 5x5 pad2 (32ch->26ch), split-K=2, bias in kg0; no relu
__global__ __launch_bounds__(256) void conv2_k(const float* __restrict__ wt2,
                                               const float* __restrict__ b2){
  __shared__ __align__(16) float in_sh[8][20][24];
  __shared__ __align__(16) float w_sh[8][25][32];
  int tile = blockIdx.x;
  int kg   = blockIdx.y;
  int b    = blockIdx.z;
  int row0 = (tile / 6) * 16, col0 = (tile % 6) * 16;
  int t = threadIdx.x;
  int og  = t >> 5;
  int pos = t & 31;
  int row = pos >> 1, x0 = (pos & 1)*8;

  float acc[8][4];
  #pragma unroll
  for (int j = 0; j < 8; j++)
    #pragma unroll
    for (int o = 0; o < 4; o++) acc[j][o] = 0.f;

  for (int cc = 0; cc < 2; cc++){
    __syncthreads();
    for (int idx = t; idx < 8*20*24; idx += 256){
      int i = idx / 480, rem = idx % 480;
      int r = rem / 24, c = rem % 24;
      int gr = row0 + r - 2, gc = col0 + c - 2;
      float v = 0.f;
      if ((unsigned)gr < 96u && (unsigned)gc < 96u){
        int ci = kg*16 + cc*8 + i;
        v = g_o1[(b*32 + ci)*HW + gr*96 + gc];
      }
      in_sh[i][r][c] = v;
    }
    for (int idx = t; idx < 8*25*32; idx += 256){
      int i = idx / 800, rem = idx % 800;
      int tap = rem / 32, oc = rem % 32;
      int ci = kg*16 + cc*8 + i;
      w_sh[i][tap][oc] = (oc < 26) ? wt2[oc*800 + ci*25 + tap] : 0.f;
    }
    __syncthreads();

    for (int i = 0; i < 8; i++){
      #pragma unroll
      for (int ky = 0; ky < 5; ky++){
        const float* rp = &in_sh[i][row + ky][x0];
        f32x4 s0 = *(const f32x4*)(rp);
        f32x4 s1 = *(const f32x4*)(rp + 4);
        f32x4 s2 = *(const f32x4*)(rp + 8);
        float seg[12] = {s0.x,s0.y,s0.z,s0.w, s1.x,s1.y,s1.z,s1.w, s2.x,s2.y,s2.z,s2.w};
        #pragma unroll
        for (int kx = 0; kx < 5; kx++){
          f32x4 wv = *(const f32x4*)&w_sh[i][ky*5 + kx][og*4];
          #pragma unroll
          for (int j = 0; j < 8; j++){
            float a = seg[kx + j];
            acc[j][0] += a*wv.x; acc[j][1] += a*wv.y;
            acc[j][2] += a*wv.z; acc[j][3] += a*wv.w;
          }
        }
      }
    }
  }

  int rg = row0 + row, cg = col0 + x0;
  #pragma unroll
  for (int o = 0; o < 4; o++){
    int slot = og*4 + o;
    if (slot < 26){
      float bias = (kg == 0) ? b2[slot] : 0.f;
      float* d = g_q + (size_t)kg*4*26*HW + ((size_t)(b*26 + slot))*HW + rg*96 + cg;
      #pragma unroll
      for (int j = 0; j < 8; j++) d[j] = acc[j][o] + bias;
    }
  }
}

// ---------------- K4: z-folded bilinear sampling -> A-matrix (bf16, A-frag swizzle)
// Channel-contiguous gathers from g_ht: thread = (px m, channel-quad cq).
__global__ __launch_bounds__(384) void sample_k(){
  __shared__ float cw[13][4][16];
  __shared__ int   co[13][4][16];
  int pt = blockIdx.x;            // 0..2303
  int t  = threadIdx.x;           // 0..383
  int b  = pt / 576;
  int p0 = (pt % 576) * 16;

  if (t < 208){
    int m = t/13, l = t%13;
    int p = p0 + m;
    const int NQ = 4*26*HW;
    float gx = fmaxf(g_q[(b*26 + l     )*HW + p] + g_q[NQ + (b*26 + l     )*HW + p], 0.f);
    float gy = fmaxf(g_q[(b*26 + 13 + l)*HW + p] + g_q[NQ + (b*26 + 13 + l)*HW + p], 0.f);
    float ix = gx * (96.f/95.f) - 0.5f;
    float iy = gy * (96.f/95.f) - 0.5f;
    float iz = (float)(l+1) * (13.f/12.f) - 0.5f;
    float z0 = floorf(iz);
    float zf = 0.f;
    #pragma unroll
    for (int dz = 0; dz < 2; dz++){
      float zc = z0 + (float)dz;
      float wz = 1.f - fabsf(iz - zc);
      if (zc >= 0.f && zc <= 12.f) zf += wz;
    }
    float x0f = floorf(ix), y0f = floorf(iy);
    #pragma unroll
    for (int dy = 0; dy < 2; dy++){
      float yc = y0f + (float)dy;
      float wy = 1.f - fabsf(iy - yc);
      bool  my = (yc >= 0.f) && (yc <= 95.f);
      int  yci = min(max((int)yc, 0), 95);
      #pragma unroll
      for (int dx = 0; dx < 2; dx++){
        float xc = x0f + (float)dx;
        float wx = 1.f - fabsf(ix - xc);
        bool  mx = (xc >= 0.f) && (xc <= 95.f);
        int  xci = min(max((int)xc, 0), 95);
        cw[l][dy*2+dx][m] = (mx && my) ? zf*wy*wx : 0.f;
        co[l][dy*2+dx][m] = yci*96 + xci;
      }
    }
  }
  __syncthreads();

  int m  = t & 15;                 // pixel in tile (lanes 0-15)
  int cq = t >> 4;                 // channel quad 0..23 (c0 = cq*4)
  int c0 = cq*4;
  const float* hb = g_ht + (size_t)b*HW*96 + c0;
  int kb3 = cq >> 3;               // which 32-block within l
  int kk  = (cq & 7)*4;            // offset within 32-block
  for (int l = 0; l < 13; l++){
    float w0 = cw[l][0][m], w1 = cw[l][1][m], w2 = cw[l][2][m], w3 = cw[l][3][m];
    int   o0 = co[l][0][m], o1 = co[l][1][m], o2 = co[l][2][m], o3 = co[l][3][m];
    f32x4 v0 = *(const f32x4*)(hb + (size_t)o0*96);
    f32x4 v1 = *(const f32x4*)(hb + (size_t)o1*96);
    f32x4 v2 = *(const f32x4*)(hb + (size_t)o2*96);
    f32x4 v3 = *(const f32x4*)(hb + (size_t)o3*96);
    f32x4 acc = w0*v0 + w1*v1 + w2*v2 + w3*v3;
    int kb = l*3 + kb3;
    u32x2 pk;
    pk.x = (uint)f2b(acc.x) | ((uint)f2b(acc.y) << 16);
    pk.y = (uint)f2b(acc.z) | ((uint)f2b(acc.w) << 16);
    *(u32x2*)&g_a[(size_t)(pt*39 + kb)*512 + m*32 + kk] = pk;
  }
}

// ---------------- K5: MFMA GEMM  [36864 x 1248] x [1248 x 288] -> g_urv (tile-major)
__global__ __launch_bounds__(256) void gemm_k(){
  __shared__ __align__(16) ushort Bsh[18*512];   // 18 KB: B[:,kb] tile
  int w    = threadIdx.x >> 6;
  int lane = threadIdx.x & 63;
  int pt   = blockIdx.x*4 + w;
  int nl   = lane & 15, quad = lane >> 4;
  int t    = threadIdx.x;

  f32x4 acc[18];
  #pragma unroll
  for (int nt = 0; nt < 18; nt++) acc[nt] = (f32x4){0.f,0.f,0.f,0.f};

  const s16x8* Ab = reinterpret_cast<const s16x8*>(g_a);
  const uint*  Bg = reinterpret_cast<const uint*>(g_b);
  uint* Bs32 = (uint*)Bsh;
  int foff = nl*4 + quad;

  for (int kb = 0; kb < 39; kb++){
    __syncthreads();
    #pragma unroll
    for (int u = 0; u < 18; u++){
      int idx = u*256 + t;
      Bs32[idx] = Bg[(idx >> 8)*39*256 + kb*256 + (idx & 255)];
    }
    __syncthreads();
    s16x8 a = Ab[(pt*39 + kb)*64 + foff];
    #pragma unroll
    for (int nt = 0; nt < 18; nt++){
      s16x8 bf = *(const s16x8*)&Bsh[nt*512 + nl*32 + quad*8];
      acc[nt] = __builtin_amdgcn_mfma_f32_16x16x32_bf16(a, bf, acc[nt], 0, 0, 0);
    }
  }

  float* dst = g_urv + (size_t)pt*4608;          // [pt][n=288][px=16]
  #pragma unroll
  for (int nt = 0; nt < 18; nt++)
    *(f32x4*)&dst[(nt*16 + nl)*16 + quad*4] = acc[nt];
}

// ---------------- K6: fused 3x3 convs on x + gating -> out
__global__ __launch_bounds__(256) void gate_k(const float* __restrict__ x,
                        const float* __restrict__ hp,
                        const float* __restrict__ uw, const float* __restrict__ ub,
                        const float* __restrict__ rw, const float* __restrict__ rb,
                        const float* __restrict__ vw, const float* __restrict__ vb,
                        const float* __restrict__ uwb, const float* __restrict__ rwb,
                        const float* __restrict__ vwb, float* __restrict__ out){
  int p  = blockIdx.x*256 + threadIdx.x;
  int oc = blockIdx.y;
  int b  = blockIdx.z;
  int h = p/96, w = p%96;
  float xU = ub[oc], xR = rb[oc], xV = vb[oc];
  const float* xb = x + b*8*HW;
  for (int ky = 0; ky < 3; ky++){
    int r = h+ky-1;
    if ((unsigned)r >= 96u) continue;
    for (int kx = 0; kx < 3; kx++){
      int c = w+kx-1;
      if ((unsigned)c >= 96u) continue;
      int off = r*96 + c;
      int wo  = ky*3 + kx;
      #pragma unroll
      for (int ic = 0; ic < 8; ic++){
        float a = xb[ic*HW + off];
        xU += a * uw[oc*72 + ic*9 + wo];
        xR += a * rw[oc*72 + ic*9 + wo];
        xV += a * vw[oc*72 + ic*9 + wo];
      }
    }
  }
  int pt = b*576 + (p >> 4), px = p & 15;
  const float* ur = g_urv + (size_t)pt*4608 + px;
  float gU = ur[(0*96 + oc)*16] + uwb[oc];
  float gR = ur[(1*96 + oc)*16] + rwb[oc];
  float gV = ur[(2*96 + oc)*16] + vwb[oc];
  float u = 1.f / (1.f + __expf(-(xU + gU)));
  float r = 1.f / (1.f + __expf(-(xR + gR)));
  float v = xV + r * gV;
  float oi = (v >= 0.f) ? v : 0.2f*v;
  float h0 = hp[(b*96 + oc)*HW + p];
  out[(b*96 + oc)*HW + p] = h0*u + oi*(1.f - u);
}

extern "C" void kernel_launch(void* const* d_in, const int* in_sizes, int n_in,
                              void* d_out, int out_size, void* d_ws, size_t ws_size,
                              hipStream_t stream){
  const float* x    = (const float*)d_in[0];
  const float* hp   = (const float*)d_in[1];
  const float* sw1  = (const float*)d_in[2];
  const float* sb1  = (const float*)d_in[3];
  const float* sw2  = (const float*)d_in[4];
  const float* sb2  = (const float*)d_in[5];
  const float* rw   = (const float*)d_in[6];
  const float* rb   = (const float*)d_in[7];
  const float* uw   = (const float*)d_in[8];
  const float* ub   = (const float*)d_in[9];
  const float* vw   = (const float*)d_in[10];
  const float* vb   = (const float*)d_in[11];
  const float* rww  = (const float*)d_in[12];
  const float* rwb  = (const float*)d_in[13];
  const float* uww  = (const float*)d_in[14];
  const float* uwb  = (const float*)d_in[15];
  const float* vww  = (const float*)d_in[16];
  const float* vwb  = (const float*)d_in[17];

  pack_b_k    <<<dim3((3*96*1248 + 255)/256), dim3(256), 0, stream>>>(uww, rww, vww);
  pack_w1b_k  <<<dim3((25*4*1024 + 255)/256), dim3(256), 0, stream>>>(sw1);
  transpose_k <<<dim3(288, 4, 4), dim3(256), 0, stream>>>(hp, x);
  conv1_mfma_k<<<dim3(144, 1, 4), dim3(64), 0, stream>>>(sb1);
  conv2_k     <<<dim3(36, 2, 4), dim3(256), 0, stream>>>(sw2, sb2);
  sample_k    <<<dim3(2304),     dim3(384), 0, stream>>>();
  gemm_k      <<<dim3(576),      dim3(256), 0, stream>>>();
  gate_k      <<<dim3(36, 96, 4), dim3(256), 0, stream>>>(x, hp,
               uw, ub, rw, rb, vw, vb, uwb, rwb, vwb, (float*)d_out);
}

// Round 3
// 404.113 us; speedup vs baseline: 1.1442x; 1.1442x over previous
//
#include <hip/hip_runtime.h>
#include <hip/hip_bf16.h>

#define HW 9216      // 96*96

typedef unsigned short ushort;
typedef unsigned int   uint;
typedef __attribute__((ext_vector_type(4))) float f32x4;
typedef __attribute__((ext_vector_type(2))) uint  u32x2;
typedef __attribute__((ext_vector_type(8))) short s16x8;

// ---------------- module-global intermediates (BSS) ----------------
__device__ float  g_o1[4*32*HW];                 // conv1 out (bias+relu) fp32
__device__ float  g_q [2*4*26*HW];               // conv2 split-K partials (bias in kg0)
__device__ __align__(16) float g_ht[4*HW*96];    // hp transposed: [b][spatial][c] fp32
__device__ __align__(16) ushort g_chi[4*(size_t)HW*128]; // concat [x;hp] transposed, bf16 HI, ch-pad to 128
__device__ __align__(16) ushort g_clo[4*(size_t)HW*128]; // bf16 LO residual
__device__ __align__(16) ushort g_w1b[28*4*2048];        // conv1 W: [(tap*4+cb)][hl][nt][16oc][32k] bf16; taps 25..27 BSS-zero
__device__ __align__(16) ushort g_a[36864*1248]; // M-matrix, bf16, MFMA A-frag swizzle
__device__ __align__(16) ushort g_b[18*39*512];  // weights,  bf16, MFMA B-frag swizzle
__device__ __align__(16) float  g_urv[2304*288*16]; // GEMM out, tile-major [pt][n][16px]

__device__ __forceinline__ ushort f2b(float f){  // fp32 -> bf16 bits, RNE
  uint x = __float_as_uint(f);
  return (ushort)((x + 0x7FFFu + ((x >> 16) & 1u)) >> 16);
}
__device__ __forceinline__ float b2f(ushort h){
  return __uint_as_float(((uint)h) << 16);
}

// ---------------- K0: pack 1x1 weights into B-fragment swizzle
// K-ordering PERMUTED: k' = l*96 + c  (weight flat index = c*13 + l)
__global__ void pack_b_k(const float* __restrict__ uww, const float* __restrict__ rww,
                         const float* __restrict__ vww){
  int i = blockIdx.x*256 + threadIdx.x;
  if (i >= 3*96*1248) return;
  int gate = i / (96*1248); int rem = i % (96*1248);
  int oc = rem / 1248;      int kp = rem % 1248;   // k' position
  int l = kp / 96, c = kp % 96;
  const float* src = (gate == 0) ? uww : ((gate == 1) ? rww : vww);
  float v = src[oc*1248 + c*13 + l];
  int n  = gate*96 + oc;
  int nt = n >> 4, nl = n & 15;
  int kb = kp >> 5, kk = kp & 31;
  g_b[(nt*39 + kb)*512 + nl*32 + kk] = f2b(v);
}

// ---------------- K0a: pack conv1 weights -> bf16 hi/lo MFMA B-fragments
// sw1 layout: (32 oc, 104 ci, 5, 5). Pad ci to 128 with zeros (makes g_c* pad inert).
__global__ void pack_w1b_k(const float* __restrict__ w1){
  int i = blockIdx.x*256 + threadIdx.x;
  if (i >= 25*4*1024) return;
  int tap = i >> 12;
  int cb  = (i >> 10) & 3;
  int oc  = (i >> 5) & 31;
  int kk  = i & 31;
  int ci  = cb*32 + kk;
  float w = (ci < 104) ? w1[oc*2600 + ci*25 + tap] : 0.f;
  ushort h = f2b(w);
  float rem = w - b2f(h);
  int base = ((tap*4 + cb) << 11) + (oc >> 4)*512 + (oc & 15)*32 + kk;
  g_w1b[base]        = h;         // hi
  g_w1b[base + 1024] = f2b(rem);  // lo
}

// ---------------- K0b: transpose hp (B,C,HW) -> g_ht (fp32) + g_chi/g_clo (bf16, ch 8..103)
//                 blockIdx.y==3 handles x -> g_chi/g_clo ch 0..7
__global__ __launch_bounds__(256) void transpose_k(const float* __restrict__ hp,
                                                   const float* __restrict__ x){
  __shared__ float tile[32][33];
  int s0 = blockIdx.x*32;          // spatial tile
  int b  = blockIdx.z;
  int t  = threadIdx.x;
  if (blockIdx.y < 3){
    int c0 = blockIdx.y*32;        // channel tile (96 = 3*32)
    for (int i = t; i < 32*32; i += 256){
      int c = i >> 5, s = i & 31;
      tile[c][s] = hp[((size_t)(b*96 + c0 + c))*HW + s0 + s];
    }
    __syncthreads();
    for (int i = t; i < 32*32; i += 256){
      int s = i >> 5, c = i & 31;
      float v = tile[c][s];
      size_t px = (size_t)b*HW + s0 + s;
      g_ht[px*96 + c0 + c] = v;
      ushort h = f2b(v);
      g_chi[px*128 + 8 + c0 + c] = h;
      g_clo[px*128 + 8 + c0 + c] = f2b(v - b2f(h));
    }
  } else {
    for (int i = t; i < 8*32; i += 256){
      int c = i >> 5, s = i & 31;
      tile[c][s] = x[((size_t)(b*8 + c))*HW + s0 + s];
    }
    __syncthreads();
    for (int i = t; i < 32*8; i += 256){
      int s = i >> 3, c = i & 7;
      float v = tile[c][s];
      size_t px = (size_t)b*HW + s0 + s;
      ushort h = f2b(v);
      g_chi[px*128 + c] = h;
      g_clo[px*128 + c] = f2b(v - b2f(h));
    }
  }
}

// ---------------- K1: conv1 5x5 pad2 (104ch->32ch) via MFMA, 3-term bf16 split
// (fp32-faithful: out += ahi*bhi + alo*bhi + ahi*blo).
// 4 waves/block, SPLIT-K OVER TAPS: wave w owns taps 7w..7w+6 (25 real taps,
// padded to 28 with BSS-zero weights; A-address clamped to tap 24 for dead taps).
// Tile: 4 rows x 16 cols of pixels per BLOCK. Cooperative halo stage (one
// exposure, shared by all waves). LDS [hl][px(160)][128ch] with 16B-chunk
// XOR swizzle (ci ^ (px&15)): A-frag reads are 2-way/bank = free.
// Partials reduced through LDS (buffer reused), epilogue row mr = wave id.
__global__ __launch_bounds__(256) void conv1_mfma_k(const float* __restrict__ b1){
  __shared__ __align__(16) ushort sh[2*160*128];   // 80 KB; reused as 32 KB reduce buf
  int t = threadIdx.x;
  int w = t >> 6, lane = t & 63;
  int nl = lane & 15, q = lane >> 4;
  int rt = blockIdx.x / 6, ct = blockIdx.x % 6;    // 24 row-tiles x 6 col-tiles
  int b  = blockIdx.z;
  int r0 = rt*4, c0 = ct*16;
  const size_t pbase = (size_t)b*HW;

  // ---- cooperative stage: 5120 16B-chunks, 20 per thread, one exposure
  #pragma unroll
  for (int i = 0; i < 20; i++){
    int idx = i*256 + t;
    int half = (i >= 10) ? 1 : 0;                  // 0: hi (g_chi), 1: lo (g_clo)
    int rem = idx - half*2560;
    int px = rem >> 4, ci = rem & 15;
    int cs = ci ^ (px & 15);                       // source-chunk swizzle
    int r = px / 20, c = px - r*20;
    int gr = r0 + r - 2, gc = c0 + c - 2;
    f32x4 v = (f32x4){0.f,0.f,0.f,0.f};
    if ((unsigned)gr < 96u && (unsigned)gc < 96u){
      const ushort* src = half ? g_clo : g_chi;
      v = *(const f32x4*)(src + ((pbase + (size_t)(gr*96 + gc)) << 7) + cs*8);
    }
    *(f32x4*)((char*)sh + (size_t)idx*16) = v;     // linear LDS write: free
  }
  __syncthreads();

  // per-wave tap set: tp = 7w + i, i = 0..6 (static unroll; dead taps have zero B)
  int kxA[7], kyA[7], tpA[7];
  #pragma unroll
  for (int i = 0; i < 7; i++){
    int tp  = 7*w + i;
    int tpc = (tp > 24) ? 24 : tp;
    kyA[i] = tpc / 5;
    kxA[i] = tpc - kyA[i]*5;
    tpA[i] = tp;
  }
  int foff = nl*32 + q*8;                          // B-frag lane offset (shorts)

  f32x4 acc[4][2];
  #pragma unroll
  for (int mr = 0; mr < 4; mr++){
    acc[mr][0] = (f32x4){0.f,0.f,0.f,0.f};
    acc[mr][1] = (f32x4){0.f,0.f,0.f,0.f};
  }

  for (int cb = 0; cb < 4; cb++){
    const ushort* bpc = g_w1b + ((size_t)cb << 11);
    s16x8 bq[3][4];
#define LOADB(slot, i) { const ushort* bp = bpc + ((size_t)tpA[i] << 13); \
    bq[slot][0] = *(const s16x8*)(bp + foff); \
    bq[slot][1] = *(const s16x8*)(bp + 512 + foff); \
    bq[slot][2] = *(const s16x8*)(bp + 1024 + foff); \
    bq[slot][3] = *(const s16x8*)(bp + 1536 + foff); }
    LOADB(0, 0); LOADB(1, 1);

    #pragma unroll
    for (int i = 0; i < 7; i++){
      if (i < 5) LOADB((i + 2) % 3, i + 2);        // static rotation (i is literal)
      int ky = kyA[i], kx = kxA[i];
      int chq = cb*4 + q;
      s16x8 ah[4], al[4];
      #pragma unroll
      for (int mr = 0; mr < 4; mr++){
        int px  = (mr + ky)*20 + kx + nl;
        int off = px*256 + (((chq ^ (px & 15))) << 4);
        ah[mr] = *(const s16x8*)((const char*)sh + off);
        al[mr] = *(const s16x8*)((const char*)sh + 40960 + off);
      }
      const int cur = i % 3;
      #pragma unroll
      for (int mr = 0; mr < 4; mr++){
        acc[mr][0] = __builtin_amdgcn_mfma_f32_16x16x32_bf16(ah[mr], bq[cur][0], acc[mr][0], 0,0,0);
        acc[mr][1] = __builtin_amdgcn_mfma_f32_16x16x32_bf16(ah[mr], bq[cur][1], acc[mr][1], 0,0,0);
      }
      #pragma unroll
      for (int mr = 0; mr < 4; mr++){
        acc[mr][0] = __builtin_amdgcn_mfma_f32_16x16x32_bf16(al[mr], bq[cur][0], acc[mr][0], 0,0,0);
        acc[mr][1] = __builtin_amdgcn_mfma_f32_16x16x32_bf16(al[mr], bq[cur][1], acc[mr][1], 0,0,0);
      }
      #pragma unroll
      for (int mr = 0; mr < 4; mr++){
        acc[mr][0] = __builtin_amdgcn_mfma_f32_16x16x32_bf16(ah[mr], bq[cur][2], acc[mr][0], 0,0,0);
        acc[mr][1] = __builtin_amdgcn_mfma_f32_16x16x32_bf16(ah[mr], bq[cur][3], acc[mr][1], 0,0,0);
      }
    }
#undef LOADB
  }

  // ---- cross-wave reduction through LDS (reuse halo buffer)
  __syncthreads();
  float* red = (float*)sh;                         // slot(mr,nt,w): stride 1 KB
  #pragma unroll
  for (int mr = 0; mr < 4; mr++)
    #pragma unroll
    for (int nt = 0; nt < 2; nt++)
      *(f32x4*)&red[(((mr*2 + nt)*4 + w) << 8) + lane*4] = acc[mr][nt];
  __syncthreads();

  int mr = w;                                      // wave w finalizes row mr = w
  #pragma unroll
  for (int nt = 0; nt < 2; nt++){
    f32x4 s = (f32x4){0.f,0.f,0.f,0.f};
    #pragma unroll
    for (int ww = 0; ww < 4; ww++)
      s += *(f32x4*)&red[(((mr*2 + nt)*4 + ww) << 8) + lane*4];
    int oc = nt*16 + nl;
    float bias = b1[oc];
    s.x = fmaxf(s.x + bias, 0.f); s.y = fmaxf(s.y + bias, 0.f);
    s.z = fmaxf(s.z + bias, 0.f); s.w = fmaxf(s.w + bias, 0.f);
    *(f32x4*)(g_o1 + ((size_t)(b*32 + oc))*HW + (size_t)(r0 + mr)*96 + c0 + q*4) = s;
  }
}

// ---------------- K3: conv2 5x5 pad2 (32ch->26ch), split-K=2, bias in kg0; no relu
__global__ __launch_bounds__(256) void conv2_k(const float* __restrict__ wt2,
                                               const float* __restrict__ b2){
  __shared__ __align__(16) float in_sh[8][20][24];
  __shared__ __align__(16) float w_sh[8][25][32];
  int tile = blockIdx.x;
  int kg   = blockIdx.y;
  int b    = blockIdx.z;
  int row0 = (tile / 6) * 16, col0 = (tile % 6) * 16;
  int t = threadIdx.x;
  int og  = t >> 5;
  int pos = t & 31;
  int row = pos >> 1, x0 = (pos & 1)*8;

  float acc[8][4];
  #pragma unroll
  for (int j = 0; j < 8; j++)
    #pragma unroll
    for (int o = 0; o < 4; o++) acc[j][o] = 0.f;

  for (int cc = 0; cc < 2; cc++){
    __syncthreads();
    for (int idx = t; idx < 8*20*24; idx += 256){
      int i = idx / 480, rem = idx % 480;
      int r = rem / 24, c = rem % 24;
      int gr = row0 + r - 2, gc = col0 + c - 2;
      float v = 0.f;
      if ((unsigned)gr < 96u && (unsigned)gc < 96u){
        int ci = kg*16 + cc*8 + i;
        v = g_o1[(b*32 + ci)*HW + gr*96 + gc];
      }
      in_sh[i][r][c] = v;
    }
    for (int idx = t; idx < 8*25*32; idx += 256){
      int i = idx / 800, rem = idx % 800;
      int tap = rem / 32, oc = rem % 32;
      int ci = kg*16 + cc*8 + i;
      w_sh[i][tap][oc] = (oc < 26) ? wt2[oc*800 + ci*25 + tap] : 0.f;
    }
    __syncthreads();

    for (int i = 0; i < 8; i++){
      #pragma unroll
      for (int ky = 0; ky < 5; ky++){
        const float* rp = &in_sh[i][row + ky][x0];
        f32x4 s0 = *(const f32x4*)(rp);
        f32x4 s1 = *(const f32x4*)(rp + 4);
        f32x4 s2 = *(const f32x4*)(rp + 8);
        float seg[12] = {s0.x,s0.y,s0.z,s0.w, s1.x,s1.y,s1.z,s1.w, s2.x,s2.y,s2.z,s2.w};
        #pragma unroll
        for (int kx = 0; kx < 5; kx++){
          f32x4 wv = *(const f32x4*)&w_sh[i][ky*5 + kx][og*4];
          #pragma unroll
          for (int j = 0; j < 8; j++){
            float a = seg[kx + j];
            acc[j][0] += a*wv.x; acc[j][1] += a*wv.y;
            acc[j][2] += a*wv.z; acc[j][3] += a*wv.w;
          }
        }
      }
    }
  }

  int rg = row0 + row, cg = col0 + x0;
  #pragma unroll
  for (int o = 0; o < 4; o++){
    int slot = og*4 + o;
    if (slot < 26){
      float bias = (kg == 0) ? b2[slot] : 0.f;
      float* d = g_q + (size_t)kg*4*26*HW + ((size_t)(b*26 + slot))*HW + rg*96 + cg;
      #pragma unroll
      for (int j = 0; j < 8; j++) d[j] = acc[j][o] + bias;
    }
  }
}

// ---------------- K4: z-folded bilinear sampling -> A-matrix (bf16, A-frag swizzle)
// Channel-contiguous gathers from g_ht: thread = (px m, channel-quad cq).
__global__ __launch_bounds__(384) void sample_k(){
  __shared__ float cw[13][4][16];
  __shared__ int   co[13][4][16];
  int pt = blockIdx.x;            // 0..2303
  int t  = threadIdx.x;           // 0..383
  int b  = pt / 576;
  int p0 = (pt % 576) * 16;

  if (t < 208){
    int m = t/13, l = t%13;
    int p = p0 + m;
    const int NQ = 4*26*HW;
    float gx = fmaxf(g_q[(b*26 + l     )*HW + p] + g_q[NQ + (b*26 + l     )*HW + p], 0.f);
    float gy = fmaxf(g_q[(b*26 + 13 + l)*HW + p] + g_q[NQ + (b*26 + 13 + l)*HW + p], 0.f);
    float ix = gx * (96.f/95.f) - 0.5f;
    float iy = gy * (96.f/95.f) - 0.5f;
    float iz = (float)(l+1) * (13.f/12.f) - 0.5f;
    float z0 = floorf(iz);
    float zf = 0.f;
    #pragma unroll
    for (int dz = 0; dz < 2; dz++){
      float zc = z0 + (float)dz;
      float wz = 1.f - fabsf(iz - zc);
      if (zc >= 0.f && zc <= 12.f) zf += wz;
    }
    float x0f = floorf(ix), y0f = floorf(iy);
    #pragma unroll
    for (int dy = 0; dy < 2; dy++){
      float yc = y0f + (float)dy;
      float wy = 1.f - fabsf(iy - yc);
      bool  my = (yc >= 0.f) && (yc <= 95.f);
      int  yci = min(max((int)yc, 0), 95);
      #pragma unroll
      for (int dx = 0; dx < 2; dx++){
        float xc = x0f + (float)dx;
        float wx = 1.f - fabsf(ix - xc);
        bool  mx = (xc >= 0.f) && (xc <= 95.f);
        int  xci = min(max((int)xc, 0), 95);
        cw[l][dy*2+dx][m] = (mx && my) ? zf*wy*wx : 0.f;
        co[l][dy*2+dx][m] = yci*96 + xci;
      }
    }
  }
  __syncthreads();

  int m  = t & 15;                 // pixel in tile (lanes 0-15)
  int cq = t >> 4;                 // channel quad 0..23 (c0 = cq*4)
  int c0 = cq*4;
  const float* hb = g_ht + (size_t)b*HW*96 + c0;
  int kb3 = cq >> 3;               // which 32-block within l
  int kk  = (cq & 7)*4;            // offset within 32-block
  for (int l = 0; l < 13; l++){
    float w0 = cw[l][0][m], w1 = cw[l][1][m], w2 = cw[l][2][m], w3 = cw[l][3][m];
    int   o0 = co[l][0][m], o1 = co[l][1][m], o2 = co[l][2][m], o3 = co[l][3][m];
    f32x4 v0 = *(const f32x4*)(hb + (size_t)o0*96);
    f32x4 v1 = *(const f32x4*)(hb + (size_t)o1*96);
    f32x4 v2 = *(const f32x4*)(hb + (size_t)o2*96);
    f32x4 v3 = *(const f32x4*)(hb + (size_t)o3*96);
    f32x4 acc = w0*v0 + w1*v1 + w2*v2 + w3*v3;
    int kb = l*3 + kb3;
    u32x2 pk;
    pk.x = (uint)f2b(acc.x) | ((uint)f2b(acc.y) << 16);
    pk.y = (uint)f2b(acc.z) | ((uint)f2b(acc.w) << 16);
    *(u32x2*)&g_a[(size_t)(pt*39 + kb)*512 + m*32 + kk] = pk;
  }
}

// ---------------- K5: MFMA GEMM  [36864 x 1248] x [1248 x 288] -> g_urv (tile-major)
__global__ __launch_bounds__(256) void gemm_k(){
  __shared__ __align__(16) ushort Bsh[18*512];   // 18 KB: B[:,kb] tile
  int w    = threadIdx.x >> 6;
  int lane = threadIdx.x & 63;
  int pt   = blockIdx.x*4 + w;
  int nl   = lane & 15, quad = lane >> 4;
  int t    = threadIdx.x;

  f32x4 acc[18];
  #pragma unroll
  for (int nt = 0; nt < 18; nt++) acc[nt] = (f32x4){0.f,0.f,0.f,0.f};

  const s16x8* Ab = reinterpret_cast<const s16x8*>(g_a);
  const uint*  Bg = reinterpret_cast<const uint*>(g_b);
  uint* Bs32 = (uint*)Bsh;
  int foff = nl*4 + quad;

  for (int kb = 0; kb < 39; kb++){
    __syncthreads();
    #pragma unroll
    for (int u = 0; u < 18; u++){
      int idx = u*256 + t;
      Bs32[idx] = Bg[(idx >> 8)*39*256 + kb*256 + (idx & 255)];
    }
    __syncthreads();
    s16x8 a = Ab[(pt*39 + kb)*64 + foff];
    #pragma unroll
    for (int nt = 0; nt < 18; nt++){
      s16x8 bf = *(const s16x8*)&Bsh[nt*512 + nl*32 + quad*8];
      acc[nt] = __builtin_amdgcn_mfma_f32_16x16x32_bf16(a, bf, acc[nt], 0, 0, 0);
    }
  }

  float* dst = g_urv + (size_t)pt*4608;          // [pt][n=288][px=16]
  #pragma unroll
  for (int nt = 0; nt < 18; nt++)
    *(f32x4*)&dst[(nt*16 + nl)*16 + quad*4] = acc[nt];
}

// ---------------- K6: fused 3x3 convs on x + gating -> out
__global__ __launch_bounds__(256) void gate_k(const float* __restrict__ x,
                        const float* __restrict__ hp,
                        const float* __restrict__ uw, const float* __restrict__ ub,
                        const float* __restrict__ rw, const float* __restrict__ rb,
                        const float* __restrict__ vw, const float* __restrict__ vb,
                        const float* __restrict__ uwb, const float* __restrict__ rwb,
                        const float* __restrict__ vwb, float* __restrict__ out){
  int p  = blockIdx.x*256 + threadIdx.x;
  int oc = blockIdx.y;
  int b  = blockIdx.z;
  int h = p/96, w = p%96;
  float xU = ub[oc], xR = rb[oc], xV = vb[oc];
  const float* xb = x + b*8*HW;
  for (int ky = 0; ky < 3; ky++){
    int r = h+ky-1;
    if ((unsigned)r >= 96u) continue;
    for (int kx = 0; kx < 3; kx++){
      int c = w+kx-1;
      if ((unsigned)c >= 96u) continue;
      int off = r*96 + c;
      int wo  = ky*3 + kx;
      #pragma unroll
      for (int ic = 0; ic < 8; ic++){
        float a = xb[ic*HW + off];
        xU += a * uw[oc*72 + ic*9 + wo];
        xR += a * rw[oc*72 + ic*9 + wo];
        xV += a * vw[oc*72 + ic*9 + wo];
      }
    }
  }
  int pt = b*576 + (p >> 4), px = p & 15;
  const float* ur = g_urv + (size_t)pt*4608 + px;
  float gU = ur[(0*96 + oc)*16] + uwb[oc];
  float gR = ur[(1*96 + oc)*16] + rwb[oc];
  float gV = ur[(2*96 + oc)*16] + vwb[oc];
  float u = 1.f / (1.f + __expf(-(xU + gU)));
  float r = 1.f / (1.f + __expf(-(xR + gR)));
  float v = xV + r * gV;
  float oi = (v >= 0.f) ? v : 0.2f*v;
  float h0 = hp[(b*96 + oc)*HW + p];
  out[(b*96 + oc)*HW + p] = h0*u + oi*(1.f - u);
}

extern "C" void kernel_launch(void* const* d_in, const int* in_sizes, int n_in,
                              void* d_out, int out_size, void* d_ws, size_t ws_size,
                              hipStream_t stream){
  const float* x    = (const float*)d_in[0];
  const float* hp   = (const float*)d_in[1];
  const float* sw1  = (const float*)d_in[2];
  const float* sb1  = (const float*)d_in[3];
  const float* sw2  = (const float*)d_in[4];
  const float* sb2  = (const float*)d_in[5];
  const float* rw   = (const float*)d_in[6];
  const float* rb   = (const float*)d_in[7];
  const float* uw   = (const float*)d_in[8];
  const float* ub   = (const float*)d_in[9];
  const float* vw   = (const float*)d_in[10];
  const float* vb   = (const float*)d_in[11];
  const float* rww  = (const float*)d_in[12];
  const float* rwb  = (const float*)d_in[13];
  const float* uww  = (const float*)d_in[14];
  const float* uwb  = (const float*)d_in[15];
  const float* vww  = (const float*)d_in[16];
  const float* vwb  = (const float*)d_in[17];

  pack_b_k    <<<dim3((3*96*1248 + 255)/256), dim3(256), 0, stream>>>(uww, rww, vww);
  pack_w1b_k  <<<dim3((25*4*1024 + 255)/256), dim3(256), 0, stream>>>(sw1);
  transpose_k <<<dim3(288, 4, 4), dim3(256), 0, stream>>>(hp, x);
  conv1_mfma_k<<<dim3(144, 1, 4), dim3(256), 0, stream>>>(sb1);
  conv2_k     <<<dim3(36, 2, 4), dim3(256), 0, stream>>>(sw2, sb2);
  sample_k    <<<dim3(2304),     dim3(384), 0, stream>>>();
  gemm_k      <<<dim3(576),      dim3(256), 0, stream>>>();
  gate_k      <<<dim3(36, 96, 4), dim3(256), 0, stream>>>(x, hp,
               uw, ub, rw, rb, vw, vb, uwb, rwb, vwb, (float*)d_out);
}

// Round 4
// 389.141 us; speedup vs baseline: 1.1882x; 1.0385x over previous
//
#include <hip/hip_runtime.h>
#include <hip/hip_bf16.h>

#define HW 9216      // 96*96

typedef unsigned short ushort;
typedef unsigned int   uint;
typedef __attribute__((ext_vector_type(4))) float f32x4;
typedef __attribute__((ext_vector_type(4))) uint  u32x4;
typedef __attribute__((ext_vector_type(4))) int   i32x4;
typedef __attribute__((ext_vector_type(8))) short s16x8;

// ---------------- module-global intermediates (BSS) ----------------
__device__ float  g_o1[4*32*HW];                 // conv1 out (bias+relu) fp32
__device__ float  g_q [2*4*26*HW];               // conv2 split-K partials (bias in kg0)
__device__ __align__(16) float g_ht[4*HW*96];    // hp transposed: [b][spatial][c] fp32
__device__ __align__(16) ushort g_chi[4*(size_t)HW*128]; // concat [x;hp] transposed, bf16 HI, ch-pad to 128
__device__ __align__(16) ushort g_clo[4*(size_t)HW*128]; // bf16 LO residual
__device__ __align__(16) ushort g_w1b[28*4*2048];        // conv1 W: [(tap*4+cb)][hl][nt][16oc][32k] bf16; taps 25..27 BSS-zero
__device__ __align__(16) ushort g_b[18*39*512];  // weights,  bf16, MFMA B-frag swizzle
__device__ __align__(16) float  g_urv[2304*288*16]; // GEMM out, tile-major [pt][n][16px]

__device__ __forceinline__ ushort f2b(float f){  // fp32 -> bf16 bits, RNE
  uint x = __float_as_uint(f);
  return (ushort)((x + 0x7FFFu + ((x >> 16) & 1u)) >> 16);
}
__device__ __forceinline__ float b2f(ushort h){
  return __uint_as_float(((uint)h) << 16);
}

// ---------------- K0: pack 1x1 weights into B-fragment swizzle
// K-ordering PERMUTED: k' = l*96 + c  (weight flat index = c*13 + l)
__global__ void pack_b_k(const float* __restrict__ uww, const float* __restrict__ rww,
                         const float* __restrict__ vww){
  int i = blockIdx.x*256 + threadIdx.x;
  if (i >= 3*96*1248) return;
  int gate = i / (96*1248); int rem = i % (96*1248);
  int oc = rem / 1248;      int kp = rem % 1248;   // k' position
  int l = kp / 96, c = kp % 96;
  const float* src = (gate == 0) ? uww : ((gate == 1) ? rww : vww);
  float v = src[oc*1248 + c*13 + l];
  int n  = gate*96 + oc;
  int nt = n >> 4, nl = n & 15;
  int kb = kp >> 5, kk = kp & 31;
  g_b[(nt*39 + kb)*512 + nl*32 + kk] = f2b(v);
}

// ---------------- K0a: pack conv1 weights -> bf16 hi/lo MFMA B-fragments
// sw1 layout: (32 oc, 104 ci, 5, 5). Pad ci to 128 with zeros (makes g_c* pad inert).
__global__ void pack_w1b_k(const float* __restrict__ w1){
  int i = blockIdx.x*256 + threadIdx.x;
  if (i >= 25*4*1024) return;
  int tap = i >> 12;
  int cb  = (i >> 10) & 3;
  int oc  = (i >> 5) & 31;
  int kk  = i & 31;
  int ci  = cb*32 + kk;
  float w = (ci < 104) ? w1[oc*2600 + ci*25 + tap] : 0.f;
  ushort h = f2b(w);
  float rem = w - b2f(h);
  int base = ((tap*4 + cb) << 11) + (oc >> 4)*512 + (oc & 15)*32 + kk;
  g_w1b[base]        = h;         // hi
  g_w1b[base + 1024] = f2b(rem);  // lo
}

// ---------------- K0b: transpose hp (B,C,HW) -> g_ht (fp32) + g_chi/g_clo (bf16, ch 8..103)
//                 blockIdx.y==3 handles x -> g_chi/g_clo ch 0..7
__global__ __launch_bounds__(256) void transpose_k(const float* __restrict__ hp,
                                                   const float* __restrict__ x){
  __shared__ float tile[32][33];
  int s0 = blockIdx.x*32;          // spatial tile
  int b  = blockIdx.z;
  int t  = threadIdx.x;
  if (blockIdx.y < 3){
    int c0 = blockIdx.y*32;        // channel tile (96 = 3*32)
    for (int i = t; i < 32*32; i += 256){
      int c = i >> 5, s = i & 31;
      tile[c][s] = hp[((size_t)(b*96 + c0 + c))*HW + s0 + s];
    }
    __syncthreads();
    for (int i = t; i < 32*32; i += 256){
      int s = i >> 5, c = i & 31;
      float v = tile[c][s];
      size_t px = (size_t)b*HW + s0 + s;
      g_ht[px*96 + c0 + c] = v;
      ushort h = f2b(v);
      g_chi[px*128 + 8 + c0 + c] = h;
      g_clo[px*128 + 8 + c0 + c] = f2b(v - b2f(h));
    }
  } else {
    for (int i = t; i < 8*32; i += 256){
      int c = i >> 5, s = i & 31;
      tile[c][s] = x[((size_t)(b*8 + c))*HW + s0 + s];
    }
    __syncthreads();
    for (int i = t; i < 32*8; i += 256){
      int s = i >> 3, c = i & 7;
      float v = tile[c][s];
      size_t px = (size_t)b*HW + s0 + s;
      ushort h = f2b(v);
      g_chi[px*128 + c] = h;
      g_clo[px*128 + c] = f2b(v - b2f(h));
    }
  }
}

// ---------------- K1: conv1 5x5 pad2 (104ch->32ch) via MFMA, 3-term bf16 split
// 4 waves/block, split-K over taps (7 taps/wave, padded to 28 with zero weights).
__global__ __launch_bounds__(256) void conv1_mfma_k(const float* __restrict__ b1){
  __shared__ __align__(16) ushort sh[2*160*128];   // 80 KB; reused as 32 KB reduce buf
  int t = threadIdx.x;
  int w = t >> 6, lane = t & 63;
  int nl = lane & 15, q = lane >> 4;
  int rt = blockIdx.x / 6, ct = blockIdx.x % 6;    // 24 row-tiles x 6 col-tiles
  int b  = blockIdx.z;
  int r0 = rt*4, c0 = ct*16;
  const size_t pbase = (size_t)b*HW;

  // ---- cooperative stage: 5120 16B-chunks, 20 per thread, one exposure
  #pragma unroll
  for (int i = 0; i < 20; i++){
    int idx = i*256 + t;
    int half = (i >= 10) ? 1 : 0;                  // 0: hi (g_chi), 1: lo (g_clo)
    int rem = idx - half*2560;
    int px = rem >> 4, ci = rem & 15;
    int cs = ci ^ (px & 15);                       // source-chunk swizzle
    int r = px / 20, c = px - r*20;
    int gr = r0 + r - 2, gc = c0 + c - 2;
    f32x4 v = (f32x4){0.f,0.f,0.f,0.f};
    if ((unsigned)gr < 96u && (unsigned)gc < 96u){
      const ushort* src = half ? g_clo : g_chi;
      v = *(const f32x4*)(src + ((pbase + (size_t)(gr*96 + gc)) << 7) + cs*8);
    }
    *(f32x4*)((char*)sh + (size_t)idx*16) = v;     // linear LDS write: free
  }
  __syncthreads();

  // per-wave tap set: tp = 7w + i, i = 0..6 (static unroll; dead taps have zero B)
  int kxA[7], kyA[7], tpA[7];
  #pragma unroll
  for (int i = 0; i < 7; i++){
    int tp  = 7*w + i;
    int tpc = (tp > 24) ? 24 : tp;
    kyA[i] = tpc / 5;
    kxA[i] = tpc - kyA[i]*5;
    tpA[i] = tp;
  }
  int foff = nl*32 + q*8;                          // B-frag lane offset (shorts)

  f32x4 acc[4][2];
  #pragma unroll
  for (int mr = 0; mr < 4; mr++){
    acc[mr][0] = (f32x4){0.f,0.f,0.f,0.f};
    acc[mr][1] = (f32x4){0.f,0.f,0.f,0.f};
  }

  for (int cb = 0; cb < 4; cb++){
    const ushort* bpc = g_w1b + ((size_t)cb << 11);
    s16x8 bq[3][4];
#define LOADB(slot, i) { const ushort* bp = bpc + ((size_t)tpA[i] << 13); \
    bq[slot][0] = *(const s16x8*)(bp + foff); \
    bq[slot][1] = *(const s16x8*)(bp + 512 + foff); \
    bq[slot][2] = *(const s16x8*)(bp + 1024 + foff); \
    bq[slot][3] = *(const s16x8*)(bp + 1536 + foff); }
    LOADB(0, 0); LOADB(1, 1);

    #pragma unroll
    for (int i = 0; i < 7; i++){
      if (i < 5) LOADB((i + 2) % 3, i + 2);        // static rotation (i is literal)
      int ky = kyA[i], kx = kxA[i];
      int chq = cb*4 + q;
      s16x8 ah[4], al[4];
      #pragma unroll
      for (int mr = 0; mr < 4; mr++){
        int px  = (mr + ky)*20 + kx + nl;
        int off = px*256 + (((chq ^ (px & 15))) << 4);
        ah[mr] = *(const s16x8*)((const char*)sh + off);
        al[mr] = *(const s16x8*)((const char*)sh + 40960 + off);
      }
      const int cur = i % 3;
      #pragma unroll
      for (int mr = 0; mr < 4; mr++){
        acc[mr][0] = __builtin_amdgcn_mfma_f32_16x16x32_bf16(ah[mr], bq[cur][0], acc[mr][0], 0,0,0);
        acc[mr][1] = __builtin_amdgcn_mfma_f32_16x16x32_bf16(ah[mr], bq[cur][1], acc[mr][1], 0,0,0);
      }
      #pragma unroll
      for (int mr = 0; mr < 4; mr++){
        acc[mr][0] = __builtin_amdgcn_mfma_f32_16x16x32_bf16(al[mr], bq[cur][0], acc[mr][0], 0,0,0);
        acc[mr][1] = __builtin_amdgcn_mfma_f32_16x16x32_bf16(al[mr], bq[cur][1], acc[mr][1], 0,0,0);
      }
      #pragma unroll
      for (int mr = 0; mr < 4; mr++){
        acc[mr][0] = __builtin_amdgcn_mfma_f32_16x16x32_bf16(ah[mr], bq[cur][2], acc[mr][0], 0,0,0);
        acc[mr][1] = __builtin_amdgcn_mfma_f32_16x16x32_bf16(ah[mr], bq[cur][3], acc[mr][1], 0,0,0);
      }
    }
#undef LOADB
  }

  // ---- cross-wave reduction through LDS (reuse halo buffer)
  __syncthreads();
  float* red = (float*)sh;                         // slot(mr,nt,w): stride 1 KB
  #pragma unroll
  for (int mr = 0; mr < 4; mr++)
    #pragma unroll
    for (int nt = 0; nt < 2; nt++)
      *(f32x4*)&red[(((mr*2 + nt)*4 + w) << 8) + lane*4] = acc[mr][nt];
  __syncthreads();

  int mr = w;                                      // wave w finalizes row mr = w
  #pragma unroll
  for (int nt = 0; nt < 2; nt++){
    f32x4 s = (f32x4){0.f,0.f,0.f,0.f};
    #pragma unroll
    for (int ww = 0; ww < 4; ww++)
      s += *(f32x4*)&red[(((mr*2 + nt)*4 + ww) << 8) + lane*4];
    int oc = nt*16 + nl;
    float bias = b1[oc];
    s.x = fmaxf(s.x + bias, 0.f); s.y = fmaxf(s.y + bias, 0.f);
    s.z = fmaxf(s.z + bias, 0.f); s.w = fmaxf(s.w + bias, 0.f);
    *(f32x4*)(g_o1 + ((size_t)(b*32 + oc))*HW + (size_t)(r0 + mr)*96 + c0 + q*4) = s;
  }
}

// ---------------- K3: conv2 5x5 pad2 (32ch->26ch), split-K=2, bias in kg0; no relu
__global__ __launch_bounds__(256) void conv2_k(const float* __restrict__ wt2,
                                               const float* __restrict__ b2){
  __shared__ __align__(16) float in_sh[8][20][24];
  __shared__ __align__(16) float w_sh[8][25][32];
  int tile = blockIdx.x;
  int kg   = blockIdx.y;
  int b    = blockIdx.z;
  int row0 = (tile / 6) * 16, col0 = (tile % 6) * 16;
  int t = threadIdx.x;
  int og  = t >> 5;
  int pos = t & 31;
  int row = pos >> 1, x0 = (pos & 1)*8;

  float acc[8][4];
  #pragma unroll
  for (int j = 0; j < 8; j++)
    #pragma unroll
    for (int o = 0; o < 4; o++) acc[j][o] = 0.f;

  for (int cc = 0; cc < 2; cc++){
    __syncthreads();
    for (int idx = t; idx < 8*20*24; idx += 256){
      int i = idx / 480, rem = idx % 480;
      int r = rem / 24, c = rem % 24;
      int gr = row0 + r - 2, gc = col0 + c - 2;
      float v = 0.f;
      if ((unsigned)gr < 96u && (unsigned)gc < 96u){
        int ci = kg*16 + cc*8 + i;
        v = g_o1[(b*32 + ci)*HW + gr*96 + gc];
      }
      in_sh[i][r][c] = v;
    }
    for (int idx = t; idx < 8*25*32; idx += 256){
      int i = idx / 800, rem = idx % 800;
      int tap = rem / 32, oc = rem % 32;
      int ci = kg*16 + cc*8 + i;
      w_sh[i][tap][oc] = (oc < 26) ? wt2[oc*800 + ci*25 + tap] : 0.f;
    }
    __syncthreads();

    for (int i = 0; i < 8; i++){
      #pragma unroll
      for (int ky = 0; ky < 5; ky++){
        const float* rp = &in_sh[i][row + ky][x0];
        f32x4 s0 = *(const f32x4*)(rp);
        f32x4 s1 = *(const f32x4*)(rp + 4);
        f32x4 s2 = *(const f32x4*)(rp + 8);
        float seg[12] = {s0.x,s0.y,s0.z,s0.w, s1.x,s1.y,s1.z,s1.w, s2.x,s2.y,s2.z,s2.w};
        #pragma unroll
        for (int kx = 0; kx < 5; kx++){
          f32x4 wv = *(const f32x4*)&w_sh[i][ky*5 + kx][og*4];
          #pragma unroll
          for (int j = 0; j < 8; j++){
            float a = seg[kx + j];
            acc[j][0] += a*wv.x; acc[j][1] += a*wv.y;
            acc[j][2] += a*wv.z; acc[j][3] += a*wv.w;
          }
        }
      }
    }
  }

  int rg = row0 + row, cg = col0 + x0;
  #pragma unroll
  for (int o = 0; o < 4; o++){
    int slot = og*4 + o;
    if (slot < 26){
      float bias = (kg == 0) ? b2[slot] : 0.f;
      float* d = g_q + (size_t)kg*4*26*HW + ((size_t)(b*26 + slot))*HW + rg*96 + cg;
      #pragma unroll
      for (int j = 0; j < 8; j++) d[j] = acc[j][o] + bias;
    }
  }
}

// ---------------- K5: FUSED sample + MFMA GEMM -> g_urv (tile-major)
// A-matrix never materialized: per (pt, kb=(l,kb3)), each lane gathers its own
// A-fragment from g_ht (4 bilinear corners x 8 channels, fp32) using per-block
// precomputed weights/offsets in LDS, packs to bf16, then 18 MFMAs vs Bsh.
// Arithmetic identical to the old sample_k path (fp32 weighting, RNE f2b).
__global__ __launch_bounds__(256) void gemm_k(){
  __shared__ __align__(16) ushort Bsh[18*512];     // 18 KB: B[:,kb] tile
  __shared__ __align__(16) float cw4[13][64][4];   // 13 KB: bilinear weights (z-folded)
  __shared__ __align__(16) int   co4[13][64][4];   // 13 KB: corner pixel offsets
  int t = threadIdx.x;
  int w = t >> 6, lane = t & 63;
  int nl = lane & 15, quad = lane >> 4;
  int blk = blockIdx.x;            // 0..575
  int b   = blk / 144;             // 4 pt per block, 144 blocks per batch
  int pbase0 = (blk % 144) * 64;   // first pixel of this block's 64-px strip
  int pt  = blk*4 + w;

  // ---- prologue: weights/offsets for 64 px x 13 l (all 256 threads)
  const int NQ = 4*26*HW;
  for (int idx = t; idx < 832; idx += 256){
    int l = idx >> 6, m = idx & 63;
    int p = pbase0 + m;
    float gx = fmaxf(g_q[(b*26 + l     )*HW + p] + g_q[NQ + (b*26 + l     )*HW + p], 0.f);
    float gy = fmaxf(g_q[(b*26 + 13 + l)*HW + p] + g_q[NQ + (b*26 + 13 + l)*HW + p], 0.f);
    float ix = gx * (96.f/95.f) - 0.5f;
    float iy = gy * (96.f/95.f) - 0.5f;
    float iz = (float)(l+1) * (13.f/12.f) - 0.5f;
    float z0 = floorf(iz);
    float zf = 0.f;
    #pragma unroll
    for (int dz = 0; dz < 2; dz++){
      float zc = z0 + (float)dz;
      float wz = 1.f - fabsf(iz - zc);
      if (zc >= 0.f && zc <= 12.f) zf += wz;
    }
    float x0f = floorf(ix), y0f = floorf(iy);
    #pragma unroll
    for (int dy = 0; dy < 2; dy++){
      float yc = y0f + (float)dy;
      float wy = 1.f - fabsf(iy - yc);
      bool  my = (yc >= 0.f) && (yc <= 95.f);
      int  yci = min(max((int)yc, 0), 95);
      #pragma unroll
      for (int dx = 0; dx < 2; dx++){
        float xc = x0f + (float)dx;
        float wx = 1.f - fabsf(ix - xc);
        bool  mx = (xc >= 0.f) && (xc <= 95.f);
        int  xci = min(max((int)xc, 0), 95);
        cw4[l][m][dy*2+dx] = (mx && my) ? zf*wy*wx : 0.f;
        co4[l][m][dy*2+dx] = yci*96 + xci;
      }
    }
  }

  f32x4 acc[18];
  #pragma unroll
  for (int nt = 0; nt < 18; nt++) acc[nt] = (f32x4){0.f,0.f,0.f,0.f};

  const uint* Bg = reinterpret_cast<const uint*>(g_b);
  uint* Bs32 = (uint*)Bsh;
  const float* hb = g_ht + (size_t)b*HW*96 + quad*8;  // + kb3*32 per iter
  int mloc = w*16 + nl;

  int l = 0, kb3 = 0;
  for (int kb = 0; kb < 39; kb++){
    __syncthreads();
    // A-gather: weights/offsets (stable LDS), then 8 x 16B corner loads
    f32x4 wv = *(const f32x4*)cw4[l][mloc];
    i32x4 ov = *(const i32x4*)co4[l][mloc];
    const float* hc = hb + kb3*32;
    const float* p0 = hc + (size_t)ov.x*96;
    const float* p1 = hc + (size_t)ov.y*96;
    const float* p2 = hc + (size_t)ov.z*96;
    const float* p3 = hc + (size_t)ov.w*96;
    f32x4 v0a = *(const f32x4*)(p0), v0b = *(const f32x4*)(p0 + 4);
    f32x4 v1a = *(const f32x4*)(p1), v1b = *(const f32x4*)(p1 + 4);
    f32x4 v2a = *(const f32x4*)(p2), v2b = *(const f32x4*)(p2 + 4);
    f32x4 v3a = *(const f32x4*)(p3), v3b = *(const f32x4*)(p3 + 4);
    // stage B tile
    #pragma unroll
    for (int u = 0; u < 18; u++){
      int idx = u*256 + t;
      Bs32[idx] = Bg[(idx >> 8)*39*256 + kb*256 + (idx & 255)];
    }
    __syncthreads();
    f32x4 aA = wv.x*v0a + wv.y*v1a + wv.z*v2a + wv.w*v3a;
    f32x4 aB = wv.x*v0b + wv.y*v1b + wv.z*v2b + wv.w*v3b;
    union { u32x4 u; s16x8 s; } cv;
    cv.u.x = (uint)f2b(aA.x) | ((uint)f2b(aA.y) << 16);
    cv.u.y = (uint)f2b(aA.z) | ((uint)f2b(aA.w) << 16);
    cv.u.z = (uint)f2b(aB.x) | ((uint)f2b(aB.y) << 16);
    cv.u.w = (uint)f2b(aB.z) | ((uint)f2b(aB.w) << 16);
    s16x8 a = cv.s;
    #pragma unroll
    for (int nt = 0; nt < 18; nt++){
      s16x8 bf = *(const s16x8*)&Bsh[nt*512 + nl*32 + quad*8];
      acc[nt] = __builtin_amdgcn_mfma_f32_16x16x32_bf16(a, bf, acc[nt], 0, 0, 0);
    }
    kb3++; if (kb3 == 3){ kb3 = 0; l++; }
  }

  float* dst = g_urv + (size_t)pt*4608;          // [pt][n=288][px=16]
  #pragma unroll
  for (int nt = 0; nt < 18; nt++)
    *(f32x4*)&dst[(nt*16 + nl)*16 + quad*4] = acc[nt];
}

// ---------------- K6: fused 3x3 convs on x + gating -> out
__global__ __launch_bounds__(256) void gate_k(const float* __restrict__ x,
                        const float* __restrict__ hp,
                        const float* __restrict__ uw, const float* __restrict__ ub,
                        const float* __restrict__ rw, const float* __restrict__ rb,
                        const float* __restrict__ vw, const float* __restrict__ vb,
                        const float* __restrict__ uwb, const float* __restrict__ rwb,
                        const float* __restrict__ vwb, float* __restrict__ out){
  int p  = blockIdx.x*256 + threadIdx.x;
  int oc = blockIdx.y;
  int b  = blockIdx.z;
  int h = p/96, w = p%96;
  float xU = ub[oc], xR = rb[oc], xV = vb[oc];
  const float* xb = x + b*8*HW;
  for (int ky = 0; ky < 3; ky++){
    int r = h+ky-1;
    if ((unsigned)r >= 96u) continue;
    for (int kx = 0; kx < 3; kx++){
      int c = w+kx-1;
      if ((unsigned)c >= 96u) continue;
      int off = r*96 + c;
      int wo  = ky*3 + kx;
      #pragma unroll
      for (int ic = 0; ic < 8; ic++){
        float a = xb[ic*HW + off];
        xU += a * uw[oc*72 + ic*9 + wo];
        xR += a * rw[oc*72 + ic*9 + wo];
        xV += a * vw[oc*72 + ic*9 + wo];
      }
    }
  }
  int pt = b*576 + (p >> 4), px = p & 15;
  const float* ur = g_urv + (size_t)pt*4608 + px;
  float gU = ur[(0*96 + oc)*16] + uwb[oc];
  float gR = ur[(1*96 + oc)*16] + rwb[oc];
  float gV = ur[(2*96 + oc)*16] + vwb[oc];
  float u = 1.f / (1.f + __expf(-(xU + gU)));
  float r = 1.f / (1.f + __expf(-(xR + gR)));
  float v = xV + r * gV;
  float oi = (v >= 0.f) ? v : 0.2f*v;
  float h0 = hp[(b*96 + oc)*HW + p];
  out[(b*96 + oc)*HW + p] = h0*u + oi*(1.f - u);
}

extern "C" void kernel_launch(void* const* d_in, const int* in_sizes, int n_in,
                              void* d_out, int out_size, void* d_ws, size_t ws_size,
                              hipStream_t stream){
  const float* x    = (const float*)d_in[0];
  const float* hp   = (const float*)d_in[1];
  const float* sw1  = (const float*)d_in[2];
  const float* sb1  = (const float*)d_in[3];
  const float* sw2  = (const float*)d_in[4];
  const float* sb2  = (const float*)d_in[5];
  const float* rw   = (const float*)d_in[6];
  const float* rb   = (const float*)d_in[7];
  const float* uw   = (const float*)d_in[8];
  const float* ub   = (const float*)d_in[9];
  const float* vw   = (const float*)d_in[10];
  const float* vb   = (const float*)d_in[11];
  const float* rww  = (const float*)d_in[12];
  const float* rwb  = (const float*)d_in[13];
  const float* uww  = (const float*)d_in[14];
  const float* uwb  = (const float*)d_in[15];
  const float* vww  = (const float*)d_in[16];
  const float* vwb  = (const float*)d_in[17];

  pack_b_k    <<<dim3((3*96*1248 + 255)/256), dim3(256), 0, stream>>>(uww, rww, vww);
  pack_w1b_k  <<<dim3((25*4*1024 + 255)/256), dim3(256), 0, stream>>>(sw1);
  transpose_k <<<dim3(288, 4, 4), dim3(256), 0, stream>>>(hp, x);
  conv1_mfma_k<<<dim3(144, 1, 4), dim3(256), 0, stream>>>(sb1);
  conv2_k     <<<dim3(36, 2, 4), dim3(256), 0, stream>>>(sw2, sb2);
  gemm_k      <<<dim3(576),      dim3(256), 0, stream>>>();
  gate_k      <<<dim3(36, 96, 4), dim3(256), 0, stream>>>(x, hp,
               uw, ub, rw, rb, vw, vb, uwb, rwb, vwb, (float*)d_out);
}

// Round 5
// 380.794 us; speedup vs baseline: 1.2142x; 1.0219x over previous
//
#include <hip/hip_runtime.h>
#include <hip/hip_bf16.h>

#define HW 9216      // 96*96

typedef unsigned short ushort;
typedef unsigned int   uint;
typedef __attribute__((ext_vector_type(4))) float f32x4;
typedef __attribute__((ext_vector_type(2))) uint  u32x2;
typedef __attribute__((ext_vector_type(4))) uint  u32x4;
typedef __attribute__((ext_vector_type(4))) int   i32x4;
typedef __attribute__((ext_vector_type(8))) short s16x8;

// ---------------- module-global intermediates (BSS) ----------------
__device__ float  g_o1[4*32*HW];                 // conv1 out (bias+relu) fp32
__device__ float  g_q [2*4*26*HW];               // conv2 split-K partials (bias in kg0)
__device__ __align__(16) float g_ht[4*HW*96];    // hp transposed: [b][spatial][c] fp32
__device__ __align__(16) ushort g_chi[4*(size_t)HW*128]; // concat [x;hp] transposed, bf16 HI, ch-pad to 128
__device__ __align__(16) ushort g_clo[4*(size_t)HW*128]; // bf16 LO residual
__device__ __align__(16) ushort g_w1b[28*4*2048];        // conv1 W: [(tap*4+cb)][hl][nt][16oc][32k] bf16; taps 25..27 BSS-zero
__device__ __align__(16) ushort g_b[18*39*512];  // weights bf16, layout [nt][kb][lane=q*16+nl][8] (conflict-free)
__device__ __align__(16) float  g_urv[2304*288*16]; // GEMM out, tile-major [pt][n][16px]

__device__ __forceinline__ ushort f2b(float f){  // fp32 -> bf16 bits, RNE
  uint x = __float_as_uint(f);
  return (ushort)((x + 0x7FFFu + ((x >> 16) & 1u)) >> 16);
}
__device__ __forceinline__ float b2f(ushort h){
  return __uint_as_float(((uint)h) << 16);
}

// ---------------- K0: pack 1x1 weights into B-fragment layout
// K-ordering PERMUTED: k' = l*96 + c  (weight flat index = c*13 + l)
// Within (nt,kb): lane-linear fragments: ushort idx = ((kk>>3)*16 + nl)*8 + (kk&7)
__global__ void pack_b_k(const float* __restrict__ uww, const float* __restrict__ rww,
                         const float* __restrict__ vww){
  int i = blockIdx.x*256 + threadIdx.x;
  if (i >= 3*96*1248) return;
  int gate = i / (96*1248); int rem = i % (96*1248);
  int oc = rem / 1248;      int kp = rem % 1248;   // k' position
  int l = kp / 96, c = kp % 96;
  const float* src = (gate == 0) ? uww : ((gate == 1) ? rww : vww);
  float v = src[oc*1248 + c*13 + l];
  int n  = gate*96 + oc;
  int nt = n >> 4, nl = n & 15;
  int kb = kp >> 5, kk = kp & 31;
  g_b[(nt*39 + kb)*512 + ((kk >> 3)*16 + nl)*8 + (kk & 7)] = f2b(v);
}

// ---------------- K0a: pack conv1 weights -> bf16 hi/lo MFMA B-fragments
// sw1 layout: (32 oc, 104 ci, 5, 5). Pad ci to 128 with zeros (makes g_c* pad inert).
__global__ void pack_w1b_k(const float* __restrict__ w1){
  int i = blockIdx.x*256 + threadIdx.x;
  if (i >= 25*4*1024) return;
  int tap = i >> 12;
  int cb  = (i >> 10) & 3;
  int oc  = (i >> 5) & 31;
  int kk  = i & 31;
  int ci  = cb*32 + kk;
  float w = (ci < 104) ? w1[oc*2600 + ci*25 + tap] : 0.f;
  ushort h = f2b(w);
  float rem = w - b2f(h);
  int base = ((tap*4 + cb) << 11) + (oc >> 4)*512 + (oc & 15)*32 + kk;
  g_w1b[base]        = h;         // hi
  g_w1b[base + 1024] = f2b(rem);  // lo
}

// ---------------- K0b: transpose hp (B,C,HW) -> g_ht (fp32) + g_chi/g_clo (bf16, ch 8..103)
//                 blockIdx.y==3 handles x -> g_chi/g_clo ch 0..7
__global__ __launch_bounds__(256) void transpose_k(const float* __restrict__ hp,
                                                   const float* __restrict__ x){
  __shared__ float tile[32][33];
  int s0 = blockIdx.x*32;          // spatial tile
  int b  = blockIdx.z;
  int t  = threadIdx.x;
  if (blockIdx.y < 3){
    int c0 = blockIdx.y*32;        // channel tile (96 = 3*32)
    for (int i = t; i < 32*32; i += 256){
      int c = i >> 5, s = i & 31;
      tile[c][s] = hp[((size_t)(b*96 + c0 + c))*HW + s0 + s];
    }
    __syncthreads();
    for (int i = t; i < 32*32; i += 256){
      int s = i >> 5, c = i & 31;
      float v = tile[c][s];
      size_t px = (size_t)b*HW + s0 + s;
      g_ht[px*96 + c0 + c] = v;
      ushort h = f2b(v);
      g_chi[px*128 + 8 + c0 + c] = h;
      g_clo[px*128 + 8 + c0 + c] = f2b(v - b2f(h));
    }
  } else {
    for (int i = t; i < 8*32; i += 256){
      int c = i >> 5, s = i & 31;
      tile[c][s] = x[((size_t)(b*8 + c))*HW + s0 + s];
    }
    __syncthreads();
    for (int i = t; i < 32*8; i += 256){
      int s = i >> 3, c = i & 7;
      float v = tile[c][s];
      size_t px = (size_t)b*HW + s0 + s;
      ushort h = f2b(v);
      g_chi[px*128 + c] = h;
      g_clo[px*128 + c] = f2b(v - b2f(h));
    }
  }
}

// ---------------- K1: conv1 5x5 pad2 (104ch->32ch) via MFMA, 3-term bf16 split
// 4 waves/block, split-K over taps (7 taps/wave, padded to 28 with zero weights).
__global__ __launch_bounds__(256) void conv1_mfma_k(const float* __restrict__ b1){
  __shared__ __align__(16) ushort sh[2*160*128];   // 80 KB; reused as 32 KB reduce buf
  int t = threadIdx.x;
  int w = t >> 6, lane = t & 63;
  int nl = lane & 15, q = lane >> 4;
  int rt = blockIdx.x / 6, ct = blockIdx.x % 6;    // 24 row-tiles x 6 col-tiles
  int b  = blockIdx.z;
  int r0 = rt*4, c0 = ct*16;
  const size_t pbase = (size_t)b*HW;

  // ---- cooperative stage: 5120 16B-chunks, 20 per thread, one exposure
  #pragma unroll
  for (int i = 0; i < 20; i++){
    int idx = i*256 + t;
    int half = (i >= 10) ? 1 : 0;                  // 0: hi (g_chi), 1: lo (g_clo)
    int rem = idx - half*2560;
    int px = rem >> 4, ci = rem & 15;
    int cs = ci ^ (px & 15);                       // source-chunk swizzle
    int r = px / 20, c = px - r*20;
    int gr = r0 + r - 2, gc = c0 + c - 2;
    f32x4 v = (f32x4){0.f,0.f,0.f,0.f};
    if ((unsigned)gr < 96u && (unsigned)gc < 96u){
      const ushort* src = half ? g_clo : g_chi;
      v = *(const f32x4*)(src + ((pbase + (size_t)(gr*96 + gc)) << 7) + cs*8);
    }
    *(f32x4*)((char*)sh + (size_t)idx*16) = v;     // linear LDS write: free
  }
  __syncthreads();

  // per-wave tap set: tp = 7w + i, i = 0..6 (static unroll; dead taps have zero B)
  int kxA[7], kyA[7], tpA[7];
  #pragma unroll
  for (int i = 0; i < 7; i++){
    int tp  = 7*w + i;
    int tpc = (tp > 24) ? 24 : tp;
    kyA[i] = tpc / 5;
    kxA[i] = tpc - kyA[i]*5;
    tpA[i] = tp;
  }
  int foff = nl*32 + q*8;                          // B-frag lane offset (shorts)

  f32x4 acc[4][2];
  #pragma unroll
  for (int mr = 0; mr < 4; mr++){
    acc[mr][0] = (f32x4){0.f,0.f,0.f,0.f};
    acc[mr][1] = (f32x4){0.f,0.f,0.f,0.f};
  }

  for (int cb = 0; cb < 4; cb++){
    const ushort* bpc = g_w1b + ((size_t)cb << 11);
    s16x8 bq[3][4];
#define LOADB(slot, i) { const ushort* bp = bpc + ((size_t)tpA[i] << 13); \
    bq[slot][0] = *(const s16x8*)(bp + foff); \
    bq[slot][1] = *(const s16x8*)(bp + 512 + foff); \
    bq[slot][2] = *(const s16x8*)(bp + 1024 + foff); \
    bq[slot][3] = *(const s16x8*)(bp + 1536 + foff); }
    LOADB(0, 0); LOADB(1, 1);

    #pragma unroll
    for (int i = 0; i < 7; i++){
      if (i < 5) LOADB((i + 2) % 3, i + 2);        // static rotation (i is literal)
      int ky = kyA[i], kx = kxA[i];
      int chq = cb*4 + q;
      s16x8 ah[4], al[4];
      #pragma unroll
      for (int mr = 0; mr < 4; mr++){
        int px  = (mr + ky)*20 + kx + nl;
        int off = px*256 + (((chq ^ (px & 15))) << 4);
        ah[mr] = *(const s16x8*)((const char*)sh + off);
        al[mr] = *(const s16x8*)((const char*)sh + 40960 + off);
      }
      const int cur = i % 3;
      #pragma unroll
      for (int mr = 0; mr < 4; mr++){
        acc[mr][0] = __builtin_amdgcn_mfma_f32_16x16x32_bf16(ah[mr], bq[cur][0], acc[mr][0], 0,0,0);
        acc[mr][1] = __builtin_amdgcn_mfma_f32_16x16x32_bf16(ah[mr], bq[cur][1], acc[mr][1], 0,0,0);
      }
      #pragma unroll
      for (int mr = 0; mr < 4; mr++){
        acc[mr][0] = __builtin_amdgcn_mfma_f32_16x16x32_bf16(al[mr], bq[cur][0], acc[mr][0], 0,0,0);
        acc[mr][1] = __builtin_amdgcn_mfma_f32_16x16x32_bf16(al[mr], bq[cur][1], acc[mr][1], 0,0,0);
      }
      #pragma unroll
      for (int mr = 0; mr < 4; mr++){
        acc[mr][0] = __builtin_amdgcn_mfma_f32_16x16x32_bf16(ah[mr], bq[cur][2], acc[mr][0], 0,0,0);
        acc[mr][1] = __builtin_amdgcn_mfma_f32_16x16x32_bf16(ah[mr], bq[cur][3], acc[mr][1], 0,0,0);
      }
    }
#undef LOADB
  }

  // ---- cross-wave reduction through LDS (reuse halo buffer)
  __syncthreads();
  float* red = (float*)sh;                         // slot(mr,nt,w): stride 1 KB
  #pragma unroll
  for (int mr = 0; mr < 4; mr++)
    #pragma unroll
    for (int nt = 0; nt < 2; nt++)
      *(f32x4*)&red[(((mr*2 + nt)*4 + w) << 8) + lane*4] = acc[mr][nt];
  __syncthreads();

  int mr = w;                                      // wave w finalizes row mr = w
  #pragma unroll
  for (int nt = 0; nt < 2; nt++){
    f32x4 s = (f32x4){0.f,0.f,0.f,0.f};
    #pragma unroll
    for (int ww = 0; ww < 4; ww++)
      s += *(f32x4*)&red[(((mr*2 + nt)*4 + ww) << 8) + lane*4];
    int oc = nt*16 + nl;
    float bias = b1[oc];
    s.x = fmaxf(s.x + bias, 0.f); s.y = fmaxf(s.y + bias, 0.f);
    s.z = fmaxf(s.z + bias, 0.f); s.w = fmaxf(s.w + bias, 0.f);
    *(f32x4*)(g_o1 + ((size_t)(b*32 + oc))*HW + (size_t)(r0 + mr)*96 + c0 + q*4) = s;
  }
}

// ---------------- K3: conv2 5x5 pad2 (32ch->26ch), split-K=2, bias in kg0; no relu
__global__ __launch_bounds__(256) void conv2_k(const float* __restrict__ wt2,
                                               const float* __restrict__ b2){
  __shared__ __align__(16) float in_sh[8][20][24];
  __shared__ __align__(16) float w_sh[8][25][32];
  int tile = blockIdx.x;
  int kg   = blockIdx.y;
  int b    = blockIdx.z;
  int row0 = (tile / 6) * 16, col0 = (tile % 6) * 16;
  int t = threadIdx.x;
  int og  = t >> 5;
  int pos = t & 31;
  int row = pos >> 1, x0 = (pos & 1)*8;

  float acc[8][4];
  #pragma unroll
  for (int j = 0; j < 8; j++)
    #pragma unroll
    for (int o = 0; o < 4; o++) acc[j][o] = 0.f;

  for (int cc = 0; cc < 2; cc++){
    __syncthreads();
    for (int idx = t; idx < 8*20*24; idx += 256){
      int i = idx / 480, rem = idx % 480;
      int r = rem / 24, c = rem % 24;
      int gr = row0 + r - 2, gc = col0 + c - 2;
      float v = 0.f;
      if ((unsigned)gr < 96u && (unsigned)gc < 96u){
        int ci = kg*16 + cc*8 + i;
        v = g_o1[(b*32 + ci)*HW + gr*96 + gc];
      }
      in_sh[i][r][c] = v;
    }
    for (int idx = t; idx < 8*25*32; idx += 256){
      int i = idx / 800, rem = idx % 800;
      int tap = rem / 32, oc = rem % 32;
      int ci = kg*16 + cc*8 + i;
      w_sh[i][tap][oc] = (oc < 26) ? wt2[oc*800 + ci*25 + tap] : 0.f;
    }
    __syncthreads();

    for (int i = 0; i < 8; i++){
      #pragma unroll
      for (int ky = 0; ky < 5; ky++){
        const float* rp = &in_sh[i][row + ky][x0];
        f32x4 s0 = *(const f32x4*)(rp);
        f32x4 s1 = *(const f32x4*)(rp + 4);
        f32x4 s2 = *(const f32x4*)(rp + 8);
        float seg[12] = {s0.x,s0.y,s0.z,s0.w, s1.x,s1.y,s1.z,s1.w, s2.x,s2.y,s2.z,s2.w};
        #pragma unroll
        for (int kx = 0; kx < 5; kx++){
          f32x4 wv = *(const f32x4*)&w_sh[i][ky*5 + kx][og*4];
          #pragma unroll
          for (int j = 0; j < 8; j++){
            float a = seg[kx + j];
            acc[j][0] += a*wv.x; acc[j][1] += a*wv.y;
            acc[j][2] += a*wv.z; acc[j][3] += a*wv.w;
          }
        }
      }
    }
  }

  int rg = row0 + row, cg = col0 + x0;
  #pragma unroll
  for (int o = 0; o < 4; o++){
    int slot = og*4 + o;
    if (slot < 26){
      float bias = (kg == 0) ? b2[slot] : 0.f;
      float* d = g_q + (size_t)kg*4*26*HW + ((size_t)(b*26 + slot))*HW + rg*96 + cg;
      #pragma unroll
      for (int j = 0; j < 8; j++) d[j] = acc[j][o] + bias;
    }
  }
}

// ---------------- K5: FUSED sample + MFMA GEMM -> g_urv (tile-major)
// Distance-1 software pipeline: stage loads (B, kb+1) and A-gathers (kb+1)
// issued before the MFMA phase of kb; raw s_barrier (NO vmcnt drain) keeps
// them in flight across barriers. Bsh layout [nt][lane][16B]: lane-linear
// ds_write AND ds_read -> zero bank conflicts. Arithmetic bit-identical to R4.
__global__ __launch_bounds__(256) void gemm_k(){
  __shared__ __align__(16) ushort Bsh[18*512];     // 18 KB, [nt][lane][8 ushorts]
  __shared__ __align__(16) float cw4[13][64][4];   // 13 KB: bilinear weights (z-folded)
  __shared__ __align__(16) int   co4[13][64][4];   // 13 KB: corner pixel offsets
  int t = threadIdx.x;
  int w = t >> 6, lane = t & 63;
  int nl = lane & 15, quad = lane >> 4;
  int blk = blockIdx.x;            // 0..575
  int b   = blk / 144;             // 4 pt per block, 144 blocks per batch
  int pbase0 = (blk % 144) * 64;   // first pixel of this block's 64-px strip
  int pt  = blk*4 + w;

  // ---- prologue: weights/offsets for 64 px x 13 l (all 256 threads)
  const int NQ = 4*26*HW;
  for (int idx = t; idx < 832; idx += 256){
    int l = idx >> 6, m = idx & 63;
    int p = pbase0 + m;
    float gx = fmaxf(g_q[(b*26 + l     )*HW + p] + g_q[NQ + (b*26 + l     )*HW + p], 0.f);
    float gy = fmaxf(g_q[(b*26 + 13 + l)*HW + p] + g_q[NQ + (b*26 + 13 + l)*HW + p], 0.f);
    float ix = gx * (96.f/95.f) - 0.5f;
    float iy = gy * (96.f/95.f) - 0.5f;
    float iz = (float)(l+1) * (13.f/12.f) - 0.5f;
    float z0 = floorf(iz);
    float zf = 0.f;
    #pragma unroll
    for (int dz = 0; dz < 2; dz++){
      float zc = z0 + (float)dz;
      float wz = 1.f - fabsf(iz - zc);
      if (zc >= 0.f && zc <= 12.f) zf += wz;
    }
    float x0f = floorf(ix), y0f = floorf(iy);
    #pragma unroll
    for (int dy = 0; dy < 2; dy++){
      float yc = y0f + (float)dy;
      float wy = 1.f - fabsf(iy - yc);
      bool  my = (yc >= 0.f) && (yc <= 95.f);
      int  yci = min(max((int)yc, 0), 95);
      #pragma unroll
      for (int dx = 0; dx < 2; dx++){
        float xc = x0f + (float)dx;
        float wx = 1.f - fabsf(ix - xc);
        bool  mx = (xc >= 0.f) && (xc <= 95.f);
        int  xci = min(max((int)xc, 0), 95);
        cw4[l][m][dy*2+dx] = (mx && my) ? zf*wy*wx : 0.f;
        co4[l][m][dy*2+dx] = yci*96 + xci;
      }
    }
  }

  f32x4 acc[18];
  #pragma unroll
  for (int nt = 0; nt < 18; nt++) acc[nt] = (f32x4){0.f,0.f,0.f,0.f};

  const u32x2* Bg8 = reinterpret_cast<const u32x2*>(g_b);
  const float* hb = g_ht + (size_t)b*HW*96 + quad*8;  // + kb3*32 per iter
  int mloc = w*16 + nl;

  f32x4 gA[8], gB[8], wA, wB;
  u32x2 sA[9], sB[9];

  // stage kb=0 (independent of cw4) — issued before the publishing barrier
  #pragma unroll
  for (int u = 0; u < 9; u++){
    int idx8 = u*256 + t;
    sA[u] = Bg8[((idx8 >> 7)*39 + 0)*128 + (idx8 & 127)];
  }
  __syncthreads();                 // publish cw4/co4 (one-time full drain, OK)

  // gather kb=0 (l=0, kb3=0) into set A
  {
    wA = *(const f32x4*)cw4[0][mloc];
    i32x4 ov_ = *(const i32x4*)co4[0][mloc];
    const float* q0_ = hb + (size_t)ov_.x*96;
    const float* q1_ = hb + (size_t)ov_.y*96;
    const float* q2_ = hb + (size_t)ov_.z*96;
    const float* q3_ = hb + (size_t)ov_.w*96;
    gA[0]=*(const f32x4*)q0_; gA[1]=*(const f32x4*)(q0_+4);
    gA[2]=*(const f32x4*)q1_; gA[3]=*(const f32x4*)(q1_+4);
    gA[4]=*(const f32x4*)q2_; gA[5]=*(const f32x4*)(q2_+4);
    gA[6]=*(const f32x4*)q3_; gA[7]=*(const f32x4*)(q3_+4);
  }
  int ln = 0, k3n = 1;             // (l, kb3) of kb+1

#define BODY(KB, GC, WC, GN, WN, SC, SN, PF) { \
  if (PF){ \
    _Pragma("unroll") \
    for (int u = 0; u < 9; u++){ \
      int idx8 = u*256 + t; \
      SN[u] = Bg8[((idx8 >> 7)*39 + (KB) + 1)*128 + (idx8 & 127)]; \
    } \
    WN = *(const f32x4*)cw4[ln][mloc]; \
    i32x4 ov_ = *(const i32x4*)co4[ln][mloc]; \
    const float* hc_ = hb + k3n*32; \
    const float* q0_ = hc_ + (size_t)ov_.x*96; \
    const float* q1_ = hc_ + (size_t)ov_.y*96; \
    const float* q2_ = hc_ + (size_t)ov_.z*96; \
    const float* q3_ = hc_ + (size_t)ov_.w*96; \
    GN[0]=*(const f32x4*)q0_; GN[1]=*(const f32x4*)(q0_+4); \
    GN[2]=*(const f32x4*)q1_; GN[3]=*(const f32x4*)(q1_+4); \
    GN[4]=*(const f32x4*)q2_; GN[5]=*(const f32x4*)(q2_+4); \
    GN[6]=*(const f32x4*)q3_; GN[7]=*(const f32x4*)(q3_+4); \
    k3n++; if (k3n == 3){ k3n = 0; ln++; } \
  } \
  _Pragma("unroll") \
  for (int u = 0; u < 9; u++){ \
    int idx8 = u*256 + t; \
    *(u32x2*)((char*)Bsh + idx8*8) = SC[u]; \
  } \
  f32x4 aA = WC.x*GC[0] + WC.y*GC[2] + WC.z*GC[4] + WC.w*GC[6]; \
  f32x4 aB = WC.x*GC[1] + WC.y*GC[3] + WC.z*GC[5] + WC.w*GC[7]; \
  union { u32x4 u4; s16x8 s8v; } cv_; \
  cv_.u4.x = (uint)f2b(aA.x) | ((uint)f2b(aA.y) << 16); \
  cv_.u4.y = (uint)f2b(aA.z) | ((uint)f2b(aA.w) << 16); \
  cv_.u4.z = (uint)f2b(aB.x) | ((uint)f2b(aB.y) << 16); \
  cv_.u4.w = (uint)f2b(aB.z) | ((uint)f2b(aB.w) << 16); \
  asm volatile("s_waitcnt lgkmcnt(0)" ::: "memory"); \
  __builtin_amdgcn_s_barrier(); \
  asm volatile("" ::: "memory"); \
  _Pragma("unroll") \
  for (int nt = 0; nt < 18; nt++){ \
    s16x8 bf = *(const s16x8*)((const char*)Bsh + nt*1024 + lane*16); \
    acc[nt] = __builtin_amdgcn_mfma_f32_16x16x32_bf16(cv_.s8v, bf, acc[nt], 0, 0, 0); \
  } \
  asm volatile("" ::: "memory"); \
  __builtin_amdgcn_s_barrier(); \
  asm volatile("" ::: "memory"); \
}

  for (int kb = 0; kb < 38; kb += 2){
    BODY(kb,     gA, wA, gB, wB, sA, sB, 1);
    BODY(kb + 1, gB, wB, gA, wA, sB, sA, 1);
  }
  BODY(38, gA, wA, gB, wB, sA, sB, 0);
#undef BODY

  float* dst = g_urv + (size_t)pt*4608;          // [pt][n=288][px=16]
  #pragma unroll
  for (int nt = 0; nt < 18; nt++)
    *(f32x4*)&dst[(nt*16 + nl)*16 + quad*4] = acc[nt];
}

// ---------------- K6: fused 3x3 convs on x + gating -> out
__global__ __launch_bounds__(256) void gate_k(const float* __restrict__ x,
                        const float* __restrict__ hp,
                        const float* __restrict__ uw, const float* __restrict__ ub,
                        const float* __restrict__ rw, const float* __restrict__ rb,
                        const float* __restrict__ vw, const float* __restrict__ vb,
                        const float* __restrict__ uwb, const float* __restrict__ rwb,
                        const float* __restrict__ vwb, float* __restrict__ out){
  int p  = blockIdx.x*256 + threadIdx.x;
  int oc = blockIdx.y;
  int b  = blockIdx.z;
  int h = p/96, w = p%96;
  float xU = ub[oc], xR = rb[oc], xV = vb[oc];
  const float* xb = x + b*8*HW;
  for (int ky = 0; ky < 3; ky++){
    int r = h+ky-1;
    if ((unsigned)r >= 96u) continue;
    for (int kx = 0; kx < 3; kx++){
      int c = w+kx-1;
      if ((unsigned)c >= 96u) continue;
      int off = r*96 + c;
      int wo  = ky*3 + kx;
      #pragma unroll
      for (int ic = 0; ic < 8; ic++){
        float a = xb[ic*HW + off];
        xU += a * uw[oc*72 + ic*9 + wo];
        xR += a * rw[oc*72 + ic*9 + wo];
        xV += a * vw[oc*72 + ic*9 + wo];
      }
    }
  }
  int pt = b*576 + (p >> 4), px = p & 15;
  const float* ur = g_urv + (size_t)pt*4608 + px;
  float gU = ur[(0*96 + oc)*16] + uwb[oc];
  float gR = ur[(1*96 + oc)*16] + rwb[oc];
  float gV = ur[(2*96 + oc)*16] + vwb[oc];
  float u = 1.f / (1.f + __expf(-(xU + gU)));
  float r = 1.f / (1.f + __expf(-(xR + gR)));
  float v = xV + r * gV;
  float oi = (v >= 0.f) ? v : 0.2f*v;
  float h0 = hp[(b*96 + oc)*HW + p];
  out[(b*96 + oc)*HW + p] = h0*u + oi*(1.f - u);
}

extern "C" void kernel_launch(void* const* d_in, const int* in_sizes, int n_in,
                              void* d_out, int out_size, void* d_ws, size_t ws_size,
                              hipStream_t stream){
  const float* x    = (const float*)d_in[0];
  const float* hp   = (const float*)d_in[1];
  const float* sw1  = (const float*)d_in[2];
  const float* sb1  = (const float*)d_in[3];
  const float* sw2  = (const float*)d_in[4];
  const float* sb2  = (const float*)d_in[5];
  const float* rw   = (const float*)d_in[6];
  const float* rb   = (const float*)d_in[7];
  const float* uw   = (const float*)d_in[8];
  const float* ub   = (const float*)d_in[9];
  const float* vw   = (const float*)d_in[10];
  const float* vb   = (const float*)d_in[11];
  const float* rww  = (const float*)d_in[12];
  const float* rwb  = (const float*)d_in[13];
  const float* uww  = (const float*)d_in[14];
  const float* uwb  = (const float*)d_in[15];
  const float* vww  = (const float*)d_in[16];
  const float* vwb  = (const float*)d_in[17];

  pack_b_k    <<<dim3((3*96*1248 + 255)/256), dim3(256), 0, stream>>>(uww, rww, vww);
  pack_w1b_k  <<<dim3((25*4*1024 + 255)/256), dim3(256), 0, stream>>>(sw1);
  transpose_k <<<dim3(288, 4, 4), dim3(256), 0, stream>>>(hp, x);
  conv1_mfma_k<<<dim3(144, 1, 4), dim3(256), 0, stream>>>(sb1);
  conv2_k     <<<dim3(36, 2, 4), dim3(256), 0, stream>>>(sw2, sb2);
  gemm_k      <<<dim3(576),      dim3(256), 0, stream>>>();
  gate_k      <<<dim3(36, 96, 4), dim3(256), 0, stream>>>(x, hp,
               uw, ub, rw, rb, vw, vb, uwb, rwb, vwb, (float*)d_out);
}

// Round 6
// 345.968 us; speedup vs baseline: 1.3365x; 1.1007x over previous
//
#include <hip/hip_runtime.h>
#include <hip/hip_bf16.h>

#define HW 9216      // 96*96

typedef unsigned short ushort;
typedef unsigned int   uint;
typedef __attribute__((ext_vector_type(4))) float f32x4;
typedef __attribute__((ext_vector_type(2))) uint  u32x2;
typedef __attribute__((ext_vector_type(4))) uint  u32x4;
typedef __attribute__((ext_vector_type(4))) int   i32x4;
typedef __attribute__((ext_vector_type(8))) short s16x8;
typedef __attribute__((ext_vector_type(8))) _Float16 f16x8;

// ---------------- module-global intermediates (BSS) ----------------
__device__ float  g_o1[4*32*HW];                 // conv1 out (bias+relu) fp32
__device__ float  g_q [2*4*26*HW];               // conv2 split-K partials (bias in kg0)
__device__ __align__(16) _Float16 g_hh[4*(size_t)HW*96]; // hp transposed fp16: [b][px][96ch] (gather table)
__device__ __align__(16) ushort g_chi[4*(size_t)HW*128]; // concat [x;hp] transposed, bf16 HI, ch-pad to 128
__device__ __align__(16) ushort g_clo[4*(size_t)HW*128]; // bf16 LO residual
__device__ __align__(16) ushort g_w1b[28*4*2048];        // conv1 W: [(tap*4+cb)][hl][nt][16oc][32k] bf16; taps 25..27 BSS-zero
__device__ __align__(16) ushort g_b[18*39*512];  // weights bf16, layout [nt][kb][lane=q*16+nl][8] (conflict-free)
__device__ __align__(16) float  g_urv[2304*288*16]; // GEMM out, tile-major [pt][n][16px]

__device__ __forceinline__ ushort f2b(float f){  // fp32 -> bf16 bits, RNE
  uint x = __float_as_uint(f);
  return (ushort)((x + 0x7FFFu + ((x >> 16) & 1u)) >> 16);
}
__device__ __forceinline__ float b2f(ushort h){
  return __uint_as_float(((uint)h) << 16);
}

// ---------------- K0: pack 1x1 weights into B-fragment layout
// K-ordering PERMUTED: k' = l*96 + c  (weight flat index = c*13 + l)
// Within (nt,kb): lane-linear fragments: ushort idx = ((kk>>3)*16 + nl)*8 + (kk&7)
__global__ void pack_b_k(const float* __restrict__ uww, const float* __restrict__ rww,
                         const float* __restrict__ vww){
  int i = blockIdx.x*256 + threadIdx.x;
  if (i >= 3*96*1248) return;
  int gate = i / (96*1248); int rem = i % (96*1248);
  int oc = rem / 1248;      int kp = rem % 1248;   // k' position
  int l = kp / 96, c = kp % 96;
  const float* src = (gate == 0) ? uww : ((gate == 1) ? rww : vww);
  float v = src[oc*1248 + c*13 + l];
  int n  = gate*96 + oc;
  int nt = n >> 4, nl = n & 15;
  int kb = kp >> 5, kk = kp & 31;
  g_b[(nt*39 + kb)*512 + ((kk >> 3)*16 + nl)*8 + (kk & 7)] = f2b(v);
}

// ---------------- K0a: pack conv1 weights -> bf16 hi/lo MFMA B-fragments
// sw1 layout: (32 oc, 104 ci, 5, 5). Pad ci to 128 with zeros (makes g_c* pad inert).
__global__ void pack_w1b_k(const float* __restrict__ w1){
  int i = blockIdx.x*256 + threadIdx.x;
  if (i >= 25*4*1024) return;
  int tap = i >> 12;
  int cb  = (i >> 10) & 3;
  int oc  = (i >> 5) & 31;
  int kk  = i & 31;
  int ci  = cb*32 + kk;
  float w = (ci < 104) ? w1[oc*2600 + ci*25 + tap] : 0.f;
  ushort h = f2b(w);
  float rem = w - b2f(h);
  int base = ((tap*4 + cb) << 11) + (oc >> 4)*512 + (oc & 15)*32 + kk;
  g_w1b[base]        = h;         // hi
  g_w1b[base + 1024] = f2b(rem);  // lo
}

// ---------------- K0b: transpose hp (B,C,HW) -> g_hh (fp16) + g_chi/g_clo (bf16, ch 8..103)
//                 blockIdx.y==3 handles x -> g_chi/g_clo ch 0..7
__global__ __launch_bounds__(256) void transpose_k(const float* __restrict__ hp,
                                                   const float* __restrict__ x){
  __shared__ float tile[32][33];
  int s0 = blockIdx.x*32;          // spatial tile
  int b  = blockIdx.z;
  int t  = threadIdx.x;
  if (blockIdx.y < 3){
    int c0 = blockIdx.y*32;        // channel tile (96 = 3*32)
    for (int i = t; i < 32*32; i += 256){
      int c = i >> 5, s = i & 31;
      tile[c][s] = hp[((size_t)(b*96 + c0 + c))*HW + s0 + s];
    }
    __syncthreads();
    for (int i = t; i < 32*32; i += 256){
      int s = i >> 5, c = i & 31;
      float v = tile[c][s];
      size_t px = (size_t)b*HW + s0 + s;
      g_hh[px*96 + c0 + c] = (_Float16)v;
      ushort h = f2b(v);
      g_chi[px*128 + 8 + c0 + c] = h;
      g_clo[px*128 + 8 + c0 + c] = f2b(v - b2f(h));
    }
  } else {
    for (int i = t; i < 8*32; i += 256){
      int c = i >> 5, s = i & 31;
      tile[c][s] = x[((size_t)(b*8 + c))*HW + s0 + s];
    }
    __syncthreads();
    for (int i = t; i < 32*8; i += 256){
      int s = i >> 3, c = i & 7;
      float v = tile[c][s];
      size_t px = (size_t)b*HW + s0 + s;
      ushort h = f2b(v);
      g_chi[px*128 + c] = h;
      g_clo[px*128 + c] = f2b(v - b2f(h));
    }
  }
}

// ---------------- K1: conv1 5x5 pad2 (104ch->32ch) via MFMA, 3-term bf16 split
// 4 waves/block, split-K over taps (7 taps/wave, padded to 28 with zero weights).
__global__ __launch_bounds__(256) void conv1_mfma_k(const float* __restrict__ b1){
  __shared__ __align__(16) ushort sh[2*160*128];   // 80 KB; reused as 32 KB reduce buf
  int t = threadIdx.x;
  int w = t >> 6, lane = t & 63;
  int nl = lane & 15, q = lane >> 4;
  int rt = blockIdx.x / 6, ct = blockIdx.x % 6;    // 24 row-tiles x 6 col-tiles
  int b  = blockIdx.z;
  int r0 = rt*4, c0 = ct*16;
  const size_t pbase = (size_t)b*HW;

  // ---- cooperative stage: 5120 16B-chunks, 20 per thread, one exposure
  #pragma unroll
  for (int i = 0; i < 20; i++){
    int idx = i*256 + t;
    int half = (i >= 10) ? 1 : 0;                  // 0: hi (g_chi), 1: lo (g_clo)
    int rem = idx - half*2560;
    int px = rem >> 4, ci = rem & 15;
    int cs = ci ^ (px & 15);                       // source-chunk swizzle
    int r = px / 20, c = px - r*20;
    int gr = r0 + r - 2, gc = c0 + c - 2;
    f32x4 v = (f32x4){0.f,0.f,0.f,0.f};
    if ((unsigned)gr < 96u && (unsigned)gc < 96u){
      const ushort* src = half ? g_clo : g_chi;
      v = *(const f32x4*)(src + ((pbase + (size_t)(gr*96 + gc)) << 7) + cs*8);
    }
    *(f32x4*)((char*)sh + (size_t)idx*16) = v;     // linear LDS write: free
  }
  __syncthreads();

  // per-wave tap set: tp = 7w + i, i = 0..6 (static unroll; dead taps have zero B)
  int kxA[7], kyA[7], tpA[7];
  #pragma unroll
  for (int i = 0; i < 7; i++){
    int tp  = 7*w + i;
    int tpc = (tp > 24) ? 24 : tp;
    kyA[i] = tpc / 5;
    kxA[i] = tpc - kyA[i]*5;
    tpA[i] = tp;
  }
  int foff = nl*32 + q*8;                          // B-frag lane offset (shorts)

  f32x4 acc[4][2];
  #pragma unroll
  for (int mr = 0; mr < 4; mr++){
    acc[mr][0] = (f32x4){0.f,0.f,0.f,0.f};
    acc[mr][1] = (f32x4){0.f,0.f,0.f,0.f};
  }

  for (int cb = 0; cb < 4; cb++){
    const ushort* bpc = g_w1b + ((size_t)cb << 11);
    s16x8 bq[3][4];
#define LOADB(slot, i) { const ushort* bp = bpc + ((size_t)tpA[i] << 13); \
    bq[slot][0] = *(const s16x8*)(bp + foff); \
    bq[slot][1] = *(const s16x8*)(bp + 512 + foff); \
    bq[slot][2] = *(const s16x8*)(bp + 1024 + foff); \
    bq[slot][3] = *(const s16x8*)(bp + 1536 + foff); }
    LOADB(0, 0); LOADB(1, 1);

    #pragma unroll
    for (int i = 0; i < 7; i++){
      if (i < 5) LOADB((i + 2) % 3, i + 2);        // static rotation (i is literal)
      int ky = kyA[i], kx = kxA[i];
      int chq = cb*4 + q;
      s16x8 ah[4], al[4];
      #pragma unroll
      for (int mr = 0; mr < 4; mr++){
        int px  = (mr + ky)*20 + kx + nl;
        int off = px*256 + (((chq ^ (px & 15))) << 4);
        ah[mr] = *(const s16x8*)((const char*)sh + off);
        al[mr] = *(const s16x8*)((const char*)sh + 40960 + off);
      }
      const int cur = i % 3;
      #pragma unroll
      for (int mr = 0; mr < 4; mr++){
        acc[mr][0] = __builtin_amdgcn_mfma_f32_16x16x32_bf16(ah[mr], bq[cur][0], acc[mr][0], 0,0,0);
        acc[mr][1] = __builtin_amdgcn_mfma_f32_16x16x32_bf16(ah[mr], bq[cur][1], acc[mr][1], 0,0,0);
      }
      #pragma unroll
      for (int mr = 0; mr < 4; mr++){
        acc[mr][0] = __builtin_amdgcn_mfma_f32_16x16x32_bf16(al[mr], bq[cur][0], acc[mr][0], 0,0,0);
        acc[mr][1] = __builtin_amdgcn_mfma_f32_16x16x32_bf16(al[mr], bq[cur][1], acc[mr][1], 0,0,0);
      }
      #pragma unroll
      for (int mr = 0; mr < 4; mr++){
        acc[mr][0] = __builtin_amdgcn_mfma_f32_16x16x32_bf16(ah[mr], bq[cur][2], acc[mr][0], 0,0,0);
        acc[mr][1] = __builtin_amdgcn_mfma_f32_16x16x32_bf16(ah[mr], bq[cur][3], acc[mr][1], 0,0,0);
      }
    }
#undef LOADB
  }

  // ---- cross-wave reduction through LDS (reuse halo buffer)
  __syncthreads();
  float* red = (float*)sh;                         // slot(mr,nt,w): stride 1 KB
  #pragma unroll
  for (int mr = 0; mr < 4; mr++)
    #pragma unroll
    for (int nt = 0; nt < 2; nt++)
      *(f32x4*)&red[(((mr*2 + nt)*4 + w) << 8) + lane*4] = acc[mr][nt];
  __syncthreads();

  int mr = w;                                      // wave w finalizes row mr = w
  #pragma unroll
  for (int nt = 0; nt < 2; nt++){
    f32x4 s = (f32x4){0.f,0.f,0.f,0.f};
    #pragma unroll
    for (int ww = 0; ww < 4; ww++)
      s += *(f32x4*)&red[(((mr*2 + nt)*4 + ww) << 8) + lane*4];
    int oc = nt*16 + nl;
    float bias = b1[oc];
    s.x = fmaxf(s.x + bias, 0.f); s.y = fmaxf(s.y + bias, 0.f);
    s.z = fmaxf(s.z + bias, 0.f); s.w = fmaxf(s.w + bias, 0.f);
    *(f32x4*)(g_o1 + ((size_t)(b*32 + oc))*HW + (size_t)(r0 + mr)*96 + c0 + q*4) = s;
  }
}

// ---------------- K3: conv2 5x5 pad2 (32ch->26ch), split-K=2, bias in kg0; no relu
__global__ __launch_bounds__(256) void conv2_k(const float* __restrict__ wt2,
                                               const float* __restrict__ b2){
  __shared__ __align__(16) float in_sh[8][20][24];
  __shared__ __align__(16) float w_sh[8][25][32];
  int tile = blockIdx.x;
  int kg   = blockIdx.y;
  int b    = blockIdx.z;
  int row0 = (tile / 6) * 16, col0 = (tile % 6) * 16;
  int t = threadIdx.x;
  int og  = t >> 5;
  int pos = t & 31;
  int row = pos >> 1, x0 = (pos & 1)*8;

  float acc[8][4];
  #pragma unroll
  for (int j = 0; j < 8; j++)
    #pragma unroll
    for (int o = 0; o < 4; o++) acc[j][o] = 0.f;

  for (int cc = 0; cc < 2; cc++){
    __syncthreads();
    for (int idx = t; idx < 8*20*24; idx += 256){
      int i = idx / 480, rem = idx % 480;
      int r = rem / 24, c = rem % 24;
      int gr = row0 + r - 2, gc = col0 + c - 2;
      float v = 0.f;
      if ((unsigned)gr < 96u && (unsigned)gc < 96u){
        int ci = kg*16 + cc*8 + i;
        v = g_o1[(b*32 + ci)*HW + gr*96 + gc];
      }
      in_sh[i][r][c] = v;
    }
    for (int idx = t; idx < 8*25*32; idx += 256){
      int i = idx / 800, rem = idx % 800;
      int tap = rem / 32, oc = rem % 32;
      int ci = kg*16 + cc*8 + i;
      w_sh[i][tap][oc] = (oc < 26) ? wt2[oc*800 + ci*25 + tap] : 0.f;
    }
    __syncthreads();

    for (int i = 0; i < 8; i++){
      #pragma unroll
      for (int ky = 0; ky < 5; ky++){
        const float* rp = &in_sh[i][row + ky][x0];
        f32x4 s0 = *(const f32x4*)(rp);
        f32x4 s1 = *(const f32x4*)(rp + 4);
        f32x4 s2 = *(const f32x4*)(rp + 8);
        float seg[12] = {s0.x,s0.y,s0.z,s0.w, s1.x,s1.y,s1.z,s1.w, s2.x,s2.y,s2.z,s2.w};
        #pragma unroll
        for (int kx = 0; kx < 5; kx++){
          f32x4 wv = *(const f32x4*)&w_sh[i][ky*5 + kx][og*4];
          #pragma unroll
          for (int j = 0; j < 8; j++){
            float a = seg[kx + j];
            acc[j][0] += a*wv.x; acc[j][1] += a*wv.y;
            acc[j][2] += a*wv.z; acc[j][3] += a*wv.w;
          }
        }
      }
    }
  }

  int rg = row0 + row, cg = col0 + x0;
  #pragma unroll
  for (int o = 0; o < 4; o++){
    int slot = og*4 + o;
    if (slot < 26){
      float bias = (kg == 0) ? b2[slot] : 0.f;
      float* d = g_q + (size_t)kg*4*26*HW + ((size_t)(b*26 + slot))*HW + rg*96 + cg;
      #pragma unroll
      for (int j = 0; j < 8; j++) d[j] = acc[j][o] + bias;
    }
  }
}

// ---------------- K5: FUSED sample + MFMA GEMM -> g_urv (tile-major)
// l=12 plane is exactly zero (z-corners OOB) -> loop 36 kb, not 39.
// Gathers from fp16 table g_hh: one 16B load per corner per lane (half the
// unique bytes/transactions of fp32). fp32 weighting, RNE bf16 pack.
// Distance-1 pipeline, raw barriers (no vmcnt drain), conflict-free Bsh.
__global__ __launch_bounds__(256) void gemm_k(){
  __shared__ __align__(16) ushort Bsh[18*512];     // 18 KB, [nt][lane][8 ushorts]
  __shared__ __align__(16) float cw4[12][64][4];   // 12 KB: bilinear weights (z-folded)
  __shared__ __align__(16) int   co4[12][64][4];   // 12 KB: corner pixel offsets
  int t = threadIdx.x;
  int w = t >> 6, lane = t & 63;
  int nl = lane & 15, quad = lane >> 4;
  int blk = blockIdx.x;            // 0..575
  int b   = blk / 144;             // 4 pt per block, 144 blocks per batch
  int pbase0 = (blk % 144) * 64;   // first pixel of this block's 64-px strip
  int pt  = blk*4 + w;

  // ---- prologue: weights/offsets for 64 px x 12 l (all 256 threads)
  const int NQ = 4*26*HW;
  for (int idx = t; idx < 768; idx += 256){
    int l = idx >> 6, m = idx & 63;
    int p = pbase0 + m;
    float gx = fmaxf(g_q[(b*26 + l     )*HW + p] + g_q[NQ + (b*26 + l     )*HW + p], 0.f);
    float gy = fmaxf(g_q[(b*26 + 13 + l)*HW + p] + g_q[NQ + (b*26 + 13 + l)*HW + p], 0.f);
    float ix = gx * (96.f/95.f) - 0.5f;
    float iy = gy * (96.f/95.f) - 0.5f;
    float iz = (float)(l+1) * (13.f/12.f) - 0.5f;
    float z0 = floorf(iz);
    float zf = 0.f;
    #pragma unroll
    for (int dz = 0; dz < 2; dz++){
      float zc = z0 + (float)dz;
      float wz = 1.f - fabsf(iz - zc);
      if (zc >= 0.f && zc <= 12.f) zf += wz;
    }
    float x0f = floorf(ix), y0f = floorf(iy);
    #pragma unroll
    for (int dy = 0; dy < 2; dy++){
      float yc = y0f + (float)dy;
      float wy = 1.f - fabsf(iy - yc);
      bool  my = (yc >= 0.f) && (yc <= 95.f);
      int  yci = min(max((int)yc, 0), 95);
      #pragma unroll
      for (int dx = 0; dx < 2; dx++){
        float xc = x0f + (float)dx;
        float wx = 1.f - fabsf(ix - xc);
        bool  mx = (xc >= 0.f) && (xc <= 95.f);
        int  xci = min(max((int)xc, 0), 95);
        cw4[l][m][dy*2+dx] = (mx && my) ? zf*wy*wx : 0.f;
        co4[l][m][dy*2+dx] = yci*96 + xci;
      }
    }
  }

  f32x4 acc[18];
  #pragma unroll
  for (int nt = 0; nt < 18; nt++) acc[nt] = (f32x4){0.f,0.f,0.f,0.f};

  const u32x2* Bg8 = reinterpret_cast<const u32x2*>(g_b);
  const _Float16* hb = g_hh + (size_t)b*HW*96 + quad*8;  // + kb3*32 per iter
  int mloc = w*16 + nl;

  f16x8 gA[4], gB[4];
  f32x4 wA, wB;
  u32x2 sA[9], sB[9];

  // stage kb=0 (independent of cw4) — issued before the publishing barrier
  #pragma unroll
  for (int u = 0; u < 9; u++){
    int idx8 = u*256 + t;
    sA[u] = Bg8[((idx8 >> 7)*39 + 0)*128 + (idx8 & 127)];
  }
  __syncthreads();                 // publish cw4/co4 (one-time full drain, OK)

  // gather kb=0 (l=0, kb3=0) into set A
  {
    wA = *(const f32x4*)cw4[0][mloc];
    i32x4 ov_ = *(const i32x4*)co4[0][mloc];
    gA[0] = *(const f16x8*)(hb + (size_t)ov_.x*96);
    gA[1] = *(const f16x8*)(hb + (size_t)ov_.y*96);
    gA[2] = *(const f16x8*)(hb + (size_t)ov_.z*96);
    gA[3] = *(const f16x8*)(hb + (size_t)ov_.w*96);
  }
  int ln = 0, k3n = 1;             // (l, kb3) of kb+1

#define BODY(KB, GC, WC, GN, WN, SC, SN, PF) { \
  if (PF){ \
    _Pragma("unroll") \
    for (int u = 0; u < 9; u++){ \
      int idx8 = u*256 + t; \
      SN[u] = Bg8[((idx8 >> 7)*39 + (KB) + 1)*128 + (idx8 & 127)]; \
    } \
    WN = *(const f32x4*)cw4[ln][mloc]; \
    i32x4 ov_ = *(const i32x4*)co4[ln][mloc]; \
    const _Float16* hc_ = hb + k3n*32; \
    GN[0] = *(const f16x8*)(hc_ + (size_t)ov_.x*96); \
    GN[1] = *(const f16x8*)(hc_ + (size_t)ov_.y*96); \
    GN[2] = *(const f16x8*)(hc_ + (size_t)ov_.z*96); \
    GN[3] = *(const f16x8*)(hc_ + (size_t)ov_.w*96); \
    k3n++; if (k3n == 3){ k3n = 0; ln++; } \
  } \
  _Pragma("unroll") \
  for (int u = 0; u < 9; u++){ \
    int idx8 = u*256 + t; \
    *(u32x2*)((char*)Bsh + idx8*8) = SC[u]; \
  } \
  float av[8]; \
  _Pragma("unroll") \
  for (int j = 0; j < 8; j++) \
    av[j] = WC.x*(float)GC[0][j] + WC.y*(float)GC[1][j] \
          + WC.z*(float)GC[2][j] + WC.w*(float)GC[3][j]; \
  union { u32x4 u4; s16x8 s8v; } cv_; \
  cv_.u4.x = (uint)f2b(av[0]) | ((uint)f2b(av[1]) << 16); \
  cv_.u4.y = (uint)f2b(av[2]) | ((uint)f2b(av[3]) << 16); \
  cv_.u4.z = (uint)f2b(av[4]) | ((uint)f2b(av[5]) << 16); \
  cv_.u4.w = (uint)f2b(av[6]) | ((uint)f2b(av[7]) << 16); \
  asm volatile("s_waitcnt lgkmcnt(0)" ::: "memory"); \
  __builtin_amdgcn_s_barrier(); \
  asm volatile("" ::: "memory"); \
  _Pragma("unroll") \
  for (int nt = 0; nt < 18; nt++){ \
    s16x8 bf = *(const s16x8*)((const char*)Bsh + nt*1024 + lane*16); \
    acc[nt] = __builtin_amdgcn_mfma_f32_16x16x32_bf16(cv_.s8v, bf, acc[nt], 0, 0, 0); \
  } \
  asm volatile("" ::: "memory"); \
  __builtin_amdgcn_s_barrier(); \
  asm volatile("" ::: "memory"); \
}

  for (int kb = 0; kb < 34; kb += 2){
    BODY(kb,     gA, wA, gB, wB, sA, sB, 1);
    BODY(kb + 1, gB, wB, gA, wA, sB, sA, 1);
  }
  BODY(34, gA, wA, gB, wB, sA, sB, 1);
  BODY(35, gB, wB, gA, wA, sB, sA, 0);
#undef BODY

  float* dst = g_urv + (size_t)pt*4608;          // [pt][n=288][px=16]
  #pragma unroll
  for (int nt = 0; nt < 18; nt++)
    *(f32x4*)&dst[(nt*16 + nl)*16 + quad*4] = acc[nt];
}

// ---------------- K6: fused 3x3 convs on x + gating -> out
__global__ __launch_bounds__(256) void gate_k(const float* __restrict__ x,
                        const float* __restrict__ hp,
                        const float* __restrict__ uw, const float* __restrict__ ub,
                        const float* __restrict__ rw, const float* __restrict__ rb,
                        const float* __restrict__ vw, const float* __restrict__ vb,
                        const float* __restrict__ uwb, const float* __restrict__ rwb,
                        const float* __restrict__ vwb, float* __restrict__ out){
  int p  = blockIdx.x*256 + threadIdx.x;
  int oc = blockIdx.y;
  int b  = blockIdx.z;
  int h = p/96, w = p%96;
  float xU = ub[oc], xR = rb[oc], xV = vb[oc];
  const float* xb = x + b*8*HW;
  for (int ky = 0; ky < 3; ky++){
    int r = h+ky-1;
    if ((unsigned)r >= 96u) continue;
    for (int kx = 0; kx < 3; kx++){
      int c = w+kx-1;
      if ((unsigned)c >= 96u) continue;
      int off = r*96 + c;
      int wo  = ky*3 + kx;
      #pragma unroll
      for (int ic = 0; ic < 8; ic++){
        float a = xb[ic*HW + off];
        xU += a * uw[oc*72 + ic*9 + wo];
        xR += a * rw[oc*72 + ic*9 + wo];
        xV += a * vw[oc*72 + ic*9 + wo];
      }
    }
  }
  int pt = b*576 + (p >> 4), px = p & 15;
  const float* ur = g_urv + (size_t)pt*4608 + px;
  float gU = ur[(0*96 + oc)*16] + uwb[oc];
  float gR = ur[(1*96 + oc)*16] + rwb[oc];
  float gV = ur[(2*96 + oc)*16] + vwb[oc];
  float u = 1.f / (1.f + __expf(-(xU + gU)));
  float r = 1.f / (1.f + __expf(-(xR + gR)));
  float v = xV + r * gV;
  float oi = (v >= 0.f) ? v : 0.2f*v;
  float h0 = hp[(b*96 + oc)*HW + p];
  out[(b*96 + oc)*HW + p] = h0*u + oi*(1.f - u);
}

extern "C" void kernel_launch(void* const* d_in, const int* in_sizes, int n_in,
                              void* d_out, int out_size, void* d_ws, size_t ws_size,
                              hipStream_t stream){
  const float* x    = (const float*)d_in[0];
  const float* hp   = (const float*)d_in[1];
  const float* sw1  = (const float*)d_in[2];
  const float* sb1  = (const float*)d_in[3];
  const float* sw2  = (const float*)d_in[4];
  const float* sb2  = (const float*)d_in[5];
  const float* rw   = (const float*)d_in[6];
  const float* rb   = (const float*)d_in[7];
  const float* uw   = (const float*)d_in[8];
  const float* ub   = (const float*)d_in[9];
  const float* vw   = (const float*)d_in[10];
  const float* vb   = (const float*)d_in[11];
  const float* rww  = (const float*)d_in[12];
  const float* rwb  = (const float*)d_in[13];
  const float* uww  = (const float*)d_in[14];
  const float* uwb  = (const float*)d_in[15];
  const float* vww  = (const float*)d_in[16];
  const float* vwb  = (const float*)d_in[17];

  pack_b_k    <<<dim3((3*96*1248 + 255)/256), dim3(256), 0, stream>>>(uww, rww, vww);
  pack_w1b_k  <<<dim3((25*4*1024 + 255)/256), dim3(256), 0, stream>>>(sw1);
  transpose_k <<<dim3(288, 4, 4), dim3(256), 0, stream>>>(hp, x);
  conv1_mfma_k<<<dim3(144, 1, 4), dim3(256), 0, stream>>>(sb1);
  conv2_k     <<<dim3(36, 2, 4), dim3(256), 0, stream>>>(sw2, sb2);
  gemm_k      <<<dim3(576),      dim3(256), 0, stream>>>();
  gate_k      <<<dim3(36, 96, 4), dim3(256), 0, stream>>>(x, hp,
               uw, ub, rw, rb, vw, vb, uwb, rwb, vwb, (float*)d_out);
}